// Round 6
// baseline (1302.822 us; speedup 1.0000x reference)
//
#include <hip/hip_runtime.h>
#include <stdint.h>
#include <stddef.h>

typedef unsigned short u16;
typedef float f4 __attribute__((ext_vector_type(4)));
typedef float f32x4 __attribute__((ext_vector_type(4)));
typedef short bf16x8 __attribute__((ext_vector_type(8)));
typedef u16 u16x4 __attribute__((ext_vector_type(4)));
typedef int i4v __attribute__((ext_vector_type(4)));

#define PAD_TOK 1026
#define LQ 61
#define NBATCH 256
#define MTOT (NBATCH * LQ)   // 15616 = 244*64 = 122*128

__device__ __forceinline__ u16 f2b(float f) {
  uint32_t x = __float_as_uint(f);
  x += 0x7fff + ((x >> 16) & 1);   // RNE
  return (u16)(x >> 16);
}
__device__ __forceinline__ float b2f(u16 u) {
  return __uint_as_float(((uint32_t)u) << 16);
}

#define GLDS(gptr, lptr) __builtin_amdgcn_global_load_lds( \
    (const __attribute__((address_space(1))) void*)(gptr), \
    (__attribute__((address_space(3))) void*)(lptr), 16, 0, 0)

__device__ __forceinline__ bf16x8 ldfrag(const u16* buf, int row, int ksl, int kg) {
  const int chunk = (ksl * 4 + kg) ^ (row & 7);
  return *(const bf16x8*)&buf[row * 64 + chunk * 8];
}

// ---------------------------------------------------------------------------
// bf16 B^T GEMM, BM x 128 tile, BK=64, 4 waves (R2-proven structure).
// ---------------------------------------------------------------------------
template<int BM>
__global__ __launch_bounds__(256) void gemm_bt(
    const u16* __restrict__ A, const u16* __restrict__ W,
    const float* __restrict__ bias,
    float* __restrict__ Cf, u16* __restrict__ Cb,
    int M, int N, int K, int Nreal, int ldc, int relu,
    long aZ, long wZ, long bZ, long cZ)
{
  constexpr int MI = BM / 32;
  const int z = blockIdx.z;
  A += z * aZ; W += z * wZ; bias += z * bZ;
  if (Cf) Cf += z * cZ;
  if (Cb) Cb += z * cZ;

  __shared__ u16 As[BM * 64];
  __shared__ u16 Bs[128 * 64];

  // bijective XCD swizzle (m204)
  const int gx = gridDim.x;
  const int nwg = gx * gridDim.y;
  const int orig = blockIdx.y * gx + blockIdx.x;
  const int q8 = nwg >> 3, r8 = nwg & 7;
  const int xcd = orig & 7, off = orig >> 3;
  const int nid = (xcd < r8 ? xcd * (q8 + 1) : r8 * (q8 + 1) + (xcd - r8) * q8) + off;
  const int bx = nid % gx, by = nid / gx;

  const int tid = threadIdx.x;
  const int wid = tid >> 6, lane = tid & 63;
  const int wr = wid >> 1, wc = wid & 1;
  const long m0 = (long)by * BM;
  const long n0 = (long)bx * 128;

  const int lr = lane >> 3;
  const int lc = lane & 7;
  const int scol = ((lc ^ lr) << 3);

  f32x4 acc[MI][4];
#pragma unroll
  for (int i = 0; i < MI; ++i)
#pragma unroll
    for (int j = 0; j < 4; ++j) acc[i][j] = (f32x4){0.f, 0.f, 0.f, 0.f};

  const u16* Abase = A + m0 * K;
  const u16* Wbase = W + n0 * K;
  const int r = lane & 15, kg = lane >> 4;

  for (int kt = 0; kt < K; kt += 64) {
#pragma unroll
    for (int c = 0; c < BM / 32; ++c) {
      const int row = wid * (BM / 4) + c * 8;
      GLDS(Abase + (long)(row + lr) * K + kt + scol, &As[row * 64]);
    }
#pragma unroll
    for (int c = 0; c < 4; ++c) {
      const int row = wid * 32 + c * 8;
      GLDS(Wbase + (long)(row + lr) * K + kt + scol, &Bs[row * 64]);
    }
    __syncthreads();

#pragma unroll
    for (int ks = 0; ks < 2; ++ks) {
      bf16x8 a[MI], b[4];
#pragma unroll
      for (int mi = 0; mi < MI; ++mi)
        a[mi] = ldfrag(As, wr * (BM / 2) + mi * 16 + r, ks, kg);
#pragma unroll
      for (int ni = 0; ni < 4; ++ni)
        b[ni] = ldfrag(Bs, wc * 64 + ni * 16 + r, ks, kg);
#pragma unroll
      for (int mi = 0; mi < MI; ++mi)
#pragma unroll
        for (int ni = 0; ni < 4; ++ni)
          acc[mi][ni] = __builtin_amdgcn_mfma_f32_16x16x32_bf16(a[mi], b[ni], acc[mi][ni], 0, 0, 0);
    }
    __syncthreads();
  }

  const int cr4 = (lane >> 4) * 4;
  const int cc = lane & 15;

  if (Cb) {
#pragma unroll
    for (int ni = 0; ni < 4; ++ni) {
      const int coll = wc * 64 + ni * 16 + cc;
      const float bv = bias[(int)n0 + coll];
#pragma unroll
      for (int mi = 0; mi < MI; ++mi) {
#pragma unroll
        for (int j = 0; j < 4; ++j) {
          const int rowl = wr * (BM / 2) + mi * 16 + cr4 + j;
          float v = acc[mi][ni][j] + bv;
          if (relu) v = fmaxf(v, 0.f);
          const int sw = (rowl & 7) << 3;
          u16* half = (coll & 64) ? Bs : As;
          half[rowl * 64 + ((coll & 63) ^ sw)] = f2b(v);
        }
      }
    }
    __syncthreads();
    constexpr int PT = BM / 16;
#pragma unroll
    for (int i = 0; i < PT; ++i) {
      const int t = i * 256 + tid;
      const int row = t >> 4, ch = t & 15;
      const int n = (int)n0 + ch * 8;
      if (n < Nreal) {
        const int phys = (ch & 7) ^ (row & 7);
        const u16* half = (ch < 8) ? As : Bs;
        bf16x8 vv = *(const bf16x8*)&half[row * 64 + phys * 8];
        *(bf16x8*)&Cb[(m0 + row) * (long)N + n] = vv;
      }
    }
  } else {
#pragma unroll
    for (int ni = 0; ni < 4; ++ni) {
      const int n = (int)n0 + wc * 64 + ni * 16 + cc;
      if (n >= Nreal) continue;
      const float bv = bias[n];
#pragma unroll
      for (int mi = 0; mi < MI; ++mi) {
#pragma unroll
        for (int j = 0; j < 4; ++j) {
          const long m = m0 + wr * (BM / 2) + mi * 16 + cr4 + j;
          float v = acc[mi][ni][j] + bv;
          if (relu) v = fmaxf(v, 0.f);
          Cf[m * ldc + n] = v;
        }
      }
    }
  }
}

// ---------------------------------------------------------------------------
// Full-row fused GEMM+LN: BM=64, BN=512(=N), 8 waves (2M x 4N), wave 32x128.
//   CA2=true : XB = LN2( LN1(A@W^T + bias + XB) + cav )   [proj]
//   CA2=false: XB = LN1(A@W^T + bias + XB)                [FF2]
// A read exactly once (no N-split); W (512xK) fully L2-resident.
// NOTE: a 64-row tile over 61-row batches spans up to THREE batches
// (m0 mod 61 in {59,60}) -> LCAV holds 3 vectors, sel in {0,1,2}.
// ---------------------------------------------------------------------------
template<bool CA2>
__global__ __launch_bounds__(512, 2) void gemmln_k(
    const u16* __restrict__ A, const u16* __restrict__ W,
    const float* __restrict__ bias,
    const u16* __restrict__ cavb,
    const float* __restrict__ s1w, const float* __restrict__ b1w,
    const float* __restrict__ s2w, const float* __restrict__ b2w,
    u16* __restrict__ XB, int K)
{
  __shared__ u16 BIGL[36864];          // LB 512x64 | LA 64x64 ; epi: 64x516
  __shared__ float LSTAT[64][8];
  __shared__ u16 LCAV[1536];           // cav for batches b0, b0+1, b0+2
  u16* const LB = BIGL;
  u16* const LA = BIGL + 32768;
  u16* const EP = BIGL;                // epilogue reuse, row stride 516

  // m204 swizzle (gx==1)
  const int nwg = gridDim.x;
  const int orig = blockIdx.x;
  const int q8 = nwg >> 3, r8 = nwg & 7;
  const int xcd = orig & 7, off = orig >> 3;
  const int by = (xcd < r8 ? xcd * (q8 + 1) : r8 * (q8 + 1) + (xcd - r8) * q8) + off;

  const int tid = threadIdx.x;
  const int wid = tid >> 6, lane = tid & 63;
  const int wm = wid >> 2, wn = wid & 3;
  const long m0 = (long)by * 64;

  const int lr = lane >> 3, lc = lane & 7;
  const int scol = ((lc ^ lr) << 3);
  const int r = lane & 15, kg = lane >> 4;

  f32x4 acc[2][8];
#pragma unroll
  for (int i = 0; i < 2; ++i)
#pragma unroll
    for (int j = 0; j < 8; ++j) acc[i][j] = (f32x4){0.f, 0.f, 0.f, 0.f};

  const u16* Abase = A + m0 * K;

  for (int kt = 0; kt < K; kt += 64) {
    {   // stage A (64 rows, 1 unit/wave) + B (512 rows, 8 units/wave)
      const int arow = wid * 8;
      GLDS(Abase + (long)(arow + lr) * K + kt + scol, &LA[arow * 64]);
#pragma unroll
      for (int c = 0; c < 8; ++c) {
        const int row = wid * 64 + c * 8;
        GLDS(W + (long)(row + lr) * K + kt + scol, &LB[row * 64]);
      }
    }
    __syncthreads();
#pragma unroll
    for (int ks = 0; ks < 2; ++ks) {
      bf16x8 a0 = ldfrag(LA, wm * 32 + r, ks, kg);
      bf16x8 a1 = ldfrag(LA, wm * 32 + 16 + r, ks, kg);
#pragma unroll
      for (int ni = 0; ni < 8; ++ni) {
        bf16x8 b = ldfrag(LB, wn * 128 + ni * 16 + r, ks, kg);
        acc[0][ni] = __builtin_amdgcn_mfma_f32_16x16x32_bf16(a0, b, acc[0][ni], 0, 0, 0);
        acc[1][ni] = __builtin_amdgcn_mfma_f32_16x16x32_bf16(a1, b, acc[1][ni], 0, 0, 0);
      }
    }
    __syncthreads();
  }

  // ---------------- fused epilogue ----------------
  const int b0 = (int)(m0 / LQ);
  const int bsplit1 = (b0 + 1) * LQ;
  const int bsplit2 = (b0 + 2) * LQ;

  // stage residual XB tile (64 rows x 512) into EP, padded stride 516
#pragma unroll
  for (int i = 0; i < 8; ++i) {
    const int t = i * 512 + tid;
    const int row = t >> 6, ch = t & 63;
    *(bf16x8*)&EP[row * 516 + ch * 8] =
        *(const bf16x8*)&XB[(m0 + row) * 512 + ch * 8];
  }
  if constexpr (CA2) {
    for (int t = tid; t < 1536; t += 512) {
      const int bb = t >> 9, c = t & 511;
      int bi = b0 + bb;
      if (bi > NBATCH - 1) bi = NBATCH - 1;
      LCAV[bb * 512 + c] = cavb[(long)bi * 512 + c];
    }
  }
  __syncthreads();

  // v = acc + bias + resid
  float bcol[8];
#pragma unroll
  for (int ni = 0; ni < 8; ++ni) bcol[ni] = bias[wn * 128 + ni * 16 + r];
#pragma unroll
  for (int mi = 0; mi < 2; ++mi)
#pragma unroll
    for (int ni = 0; ni < 8; ++ni) {
      const int col = wn * 128 + ni * 16 + r;
#pragma unroll
      for (int j = 0; j < 4; ++j) {
        const int row = wm * 32 + mi * 16 + kg * 4 + j;
        acc[mi][ni][j] += bcol[ni] + b2f(EP[row * 516 + col]);
      }
    }

  // ---- stats round 1 ----
#pragma unroll
  for (int mi = 0; mi < 2; ++mi)
#pragma unroll
    for (int j = 0; j < 4; ++j) {
      float s1 = 0.f, s2 = 0.f;
#pragma unroll
      for (int ni = 0; ni < 8; ++ni) {
        const float v = acc[mi][ni][j];
        s1 += v; s2 += v * v;
      }
#pragma unroll
      for (int o = 1; o < 16; o <<= 1) {
        s1 += __shfl_xor(s1, o);
        s2 += __shfl_xor(s2, o);
      }
      if (r == 0) {
        const int row = wm * 32 + mi * 16 + kg * 4 + j;
        LSTAT[row][wn] = s1;
        LSTAT[row][4 + wn] = s2;
      }
    }
  __syncthreads();

  // ---- apply LN1 ----
  float sc[8], bc[8];
#pragma unroll
  for (int ni = 0; ni < 8; ++ni) {
    const int col = wn * 128 + ni * 16 + r;
    sc[ni] = s1w[col]; bc[ni] = b1w[col];
  }
#pragma unroll
  for (int mi = 0; mi < 2; ++mi)
#pragma unroll
    for (int j = 0; j < 4; ++j) {
      const int row = wm * 32 + mi * 16 + kg * 4 + j;
      const float S1 = LSTAT[row][0] + LSTAT[row][1] + LSTAT[row][2] + LSTAT[row][3];
      const float S2 = LSTAT[row][4] + LSTAT[row][5] + LSTAT[row][6] + LSTAT[row][7];
      const float mean = S1 * (1.f / 512.f);
      const float var = S2 * (1.f / 512.f) - mean * mean;
      const float rstd = rsqrtf(var + 1e-5f);
#pragma unroll
      for (int ni = 0; ni < 8; ++ni)
        acc[mi][ni][j] = (acc[mi][ni][j] - mean) * rstd * sc[ni] + bc[ni];
    }

  if constexpr (CA2) {
    // + cav (3-batch-aware select), then LN2
#pragma unroll
    for (int mi = 0; mi < 2; ++mi)
#pragma unroll
      for (int j = 0; j < 4; ++j) {
        const int row = wm * 32 + mi * 16 + kg * 4 + j;
        const int gr = (int)m0 + row;
        const int sel = (gr >= bsplit2) ? 2 : ((gr >= bsplit1) ? 1 : 0);
#pragma unroll
        for (int ni = 0; ni < 8; ++ni) {
          const int col = wn * 128 + ni * 16 + r;
          acc[mi][ni][j] += b2f(LCAV[sel * 512 + col]);
        }
      }
    __syncthreads();   // everyone done reading round-1 LSTAT
#pragma unroll
    for (int mi = 0; mi < 2; ++mi)
#pragma unroll
      for (int j = 0; j < 4; ++j) {
        float s1 = 0.f, s2 = 0.f;
#pragma unroll
        for (int ni = 0; ni < 8; ++ni) {
          const float v = acc[mi][ni][j];
          s1 += v; s2 += v * v;
        }
#pragma unroll
        for (int o = 1; o < 16; o <<= 1) {
          s1 += __shfl_xor(s1, o);
          s2 += __shfl_xor(s2, o);
        }
        if (r == 0) {
          const int row = wm * 32 + mi * 16 + kg * 4 + j;
          LSTAT[row][wn] = s1;
          LSTAT[row][4 + wn] = s2;
        }
      }
    __syncthreads();
#pragma unroll
    for (int ni = 0; ni < 8; ++ni) {
      const int col = wn * 128 + ni * 16 + r;
      sc[ni] = s2w[col]; bc[ni] = b2w[col];
    }
#pragma unroll
    for (int mi = 0; mi < 2; ++mi)
#pragma unroll
      for (int j = 0; j < 4; ++j) {
        const int row = wm * 32 + mi * 16 + kg * 4 + j;
        const float S1 = LSTAT[row][0] + LSTAT[row][1] + LSTAT[row][2] + LSTAT[row][3];
        const float S2 = LSTAT[row][4] + LSTAT[row][5] + LSTAT[row][6] + LSTAT[row][7];
        const float mean = S1 * (1.f / 512.f);
        const float var = S2 * (1.f / 512.f) - mean * mean;
        const float rstd = rsqrtf(var + 1e-5f);
#pragma unroll
        for (int ni = 0; ni < 8; ++ni)
          acc[mi][ni][j] = (acc[mi][ni][j] - mean) * rstd * sc[ni] + bc[ni];
      }
  }

  // write bf16 to EP, then coalesced store to XB
#pragma unroll
  for (int mi = 0; mi < 2; ++mi)
#pragma unroll
    for (int ni = 0; ni < 8; ++ni) {
      const int col = wn * 128 + ni * 16 + r;
#pragma unroll
      for (int j = 0; j < 4; ++j) {
        const int row = wm * 32 + mi * 16 + kg * 4 + j;
        EP[row * 516 + col] = f2b(acc[mi][ni][j]);
      }
    }
  __syncthreads();
#pragma unroll
  for (int i = 0; i < 8; ++i) {
    const int t = i * 512 + tid;
    const int row = t >> 6, ch = t & 63;
    *(bf16x8*)&XB[(m0 + row) * 512 + ch * 8] =
        *(const bf16x8*)&EP[row * 516 + ch * 8];
  }
}

// ---------------------------------------------------------------------------
// Fused self-attention: one block per (batch, head).
// ---------------------------------------------------------------------------
__global__ __launch_bounds__(256) void attn_k(const u16* __restrict__ qkv,
                                              const int* __restrict__ tgt,
                                              u16* __restrict__ outp)
{
  __shared__ u16 Qs[64 * 72];
  __shared__ u16 Ks[64 * 72];
  __shared__ u16 Vt[64 * 72];
  __shared__ float S[64 * 65];
  __shared__ int stok[64];

  const int bid = blockIdx.x;
  const int b = bid >> 3, h = bid & 7;
  const int tid = threadIdx.x;
  const int tr = tid >> 2, seg = tid & 3;

  if (tid < 64) stok[tid] = (tid < 61) ? tgt[b * 62 + tid] : -1;

  const long rowbase = ((long)(b * LQ + tr)) * 1536 + h * 64;
  if (tr < LQ) {
    const i4v* qsrc = (const i4v*)(qkv + rowbase + seg * 16);
    i4v q0 = qsrc[0], q1 = qsrc[1];
    *(i4v*)&Qs[tr * 72 + seg * 16] = q0;
    *(i4v*)&Qs[tr * 72 + seg * 16 + 8] = q1;
    const i4v* ksrc = (const i4v*)(qkv + rowbase + 512 + seg * 16);
    i4v k0 = ksrc[0], k1 = ksrc[1];
    *(i4v*)&Ks[tr * 72 + seg * 16] = k0;
    *(i4v*)&Ks[tr * 72 + seg * 16 + 8] = k1;
    const u16* vsrc = qkv + rowbase + 1024 + seg * 16;
#pragma unroll
    for (int i = 0; i < 16; ++i) Vt[(seg * 16 + i) * 72 + tr] = vsrc[i];
  } else {
    i4v zz = {0, 0, 0, 0};
    *(i4v*)&Qs[tr * 72 + seg * 16] = zz;
    *(i4v*)&Qs[tr * 72 + seg * 16 + 8] = zz;
    *(i4v*)&Ks[tr * 72 + seg * 16] = zz;
    *(i4v*)&Ks[tr * 72 + seg * 16 + 8] = zz;
#pragma unroll
    for (int i = 0; i < 16; ++i) Vt[(seg * 16 + i) * 72 + tr] = 0;
  }
  __syncthreads();

  const int lane = tid & 63, w = tid >> 6;
  const int r = lane & 15, kg = lane >> 4;

  {   // QK^T
    f32x4 s[4];
#pragma unroll
    for (int ni = 0; ni < 4; ++ni) s[ni] = (f32x4){0.f, 0.f, 0.f, 0.f};
    bf16x8 a0 = *(const bf16x8*)&Qs[(w * 16 + r) * 72 + kg * 8];
    bf16x8 a1 = *(const bf16x8*)&Qs[(w * 16 + r) * 72 + 32 + kg * 8];
#pragma unroll
    for (int ni = 0; ni < 4; ++ni) {
      bf16x8 b0 = *(const bf16x8*)&Ks[(ni * 16 + r) * 72 + kg * 8];
      bf16x8 b1 = *(const bf16x8*)&Ks[(ni * 16 + r) * 72 + 32 + kg * 8];
      s[ni] = __builtin_amdgcn_mfma_f32_16x16x32_bf16(a0, b0, s[ni], 0, 0, 0);
      s[ni] = __builtin_amdgcn_mfma_f32_16x16x32_bf16(a1, b1, s[ni], 0, 0, 0);
    }
#pragma unroll
    for (int ni = 0; ni < 4; ++ni)
#pragma unroll
      for (int j = 0; j < 4; ++j)
        S[(w * 16 + kg * 4 + j) * 65 + ni * 16 + r] = s[ni][j];
  }
  __syncthreads();

  {   // masked softmax
    const int row = tid >> 2, g = tid & 3;
    float vals[16];
    float mx = -3e38f;
#pragma unroll
    for (int i = 0; i < 16; ++i) {
      const int k = g * 16 + i;
      float v = S[row * 65 + k] * 0.125f;
      const bool ok = (k <= row) && (k < LQ) && (stok[k] != PAD_TOK);
      v = ok ? v : -1e30f;
      vals[i] = v;
      mx = fmaxf(mx, v);
    }
    mx = fmaxf(mx, __shfl_xor(mx, 1));
    mx = fmaxf(mx, __shfl_xor(mx, 2));
    float sum = 0.f;
#pragma unroll
    for (int i = 0; i < 16; ++i) { float e = __expf(vals[i] - mx); vals[i] = e; sum += e; }
    sum += __shfl_xor(sum, 1);
    sum += __shfl_xor(sum, 2);
    const float inv = 1.f / sum;
#pragma unroll
    for (int i = 0; i < 16; ++i) Qs[row * 72 + g * 16 + i] = f2b(vals[i] * inv);
  }
  __syncthreads();

  {   // PV, swizzled bounce into Ks
    f32x4 o[4];
#pragma unroll
    for (int ni = 0; ni < 4; ++ni) o[ni] = (f32x4){0.f, 0.f, 0.f, 0.f};
    bf16x8 a0 = *(const bf16x8*)&Qs[(w * 16 + r) * 72 + kg * 8];
    bf16x8 a1 = *(const bf16x8*)&Qs[(w * 16 + r) * 72 + 32 + kg * 8];
#pragma unroll
    for (int ni = 0; ni < 4; ++ni) {
      bf16x8 b0 = *(const bf16x8*)&Vt[(ni * 16 + r) * 72 + kg * 8];
      bf16x8 b1 = *(const bf16x8*)&Vt[(ni * 16 + r) * 72 + 32 + kg * 8];
      o[ni] = __builtin_amdgcn_mfma_f32_16x16x32_bf16(a0, b0, o[ni], 0, 0, 0);
      o[ni] = __builtin_amdgcn_mfma_f32_16x16x32_bf16(a1, b1, o[ni], 0, 0, 0);
    }
#pragma unroll
    for (int ni = 0; ni < 4; ++ni)
#pragma unroll
      for (int j = 0; j < 4; ++j) {
        const int qrow = w * 16 + kg * 4 + j;
        const int col = ni * 16 + r;
        Ks[qrow * 64 + (col ^ ((qrow & 7) << 3))] = f2b(o[ni][j]);
      }
  }
  __syncthreads();

  {   // coalesced O store
    const int row = tid >> 2, sub = tid & 3;
    if (row < LQ) {
      const long obase = ((long)(b * LQ + row)) * 512 + h * 64;
#pragma unroll
      for (int i = 0; i < 2; ++i) {
        const int ch = i * 4 + sub;
        const int phys = ch ^ (row & 7);
        bf16x8 vv = *(const bf16x8*)&Ks[row * 64 + phys * 8];
        *(bf16x8*)&outp[obase + ch * 8] = vv;
      }
    }
  }
}

// Embedding: xb[m] = bf16(emb[tok] + point_out[b] + pos_embed[t])
__global__ __launch_bounds__(256) void embed_k(const float* __restrict__ emb,
                                               const float* __restrict__ pout,
                                               const float* __restrict__ pos,
                                               const int* __restrict__ tgt,
                                               u16* __restrict__ XB)
{
  const int m = blockIdx.x * 4 + (threadIdx.x >> 6);
  const int lane = threadIdx.x & 63;
  const int b = m / LQ, t = m % LQ;
  const int tok = tgt[b * 62 + t];
  const int d0 = lane * 8;
  const f4* e = (const f4*)(emb + (long)tok * 512 + d0);
  const f4* p = (const f4*)(pout + (long)b * 512 + d0);
  const f4* q = (const f4*)(pos + (long)t * 512 + d0);
  f4 v0 = e[0] + p[0] + q[0];
  f4 v1 = e[1] + p[1] + q[1];
  u16x4* xb = (u16x4*)(XB + (long)m * 512 + d0);
  xb[0] = (u16x4){f2b(v0[0]), f2b(v0[1]), f2b(v0[2]), f2b(v0[3])};
  xb[1] = (u16x4){f2b(v1[0]), f2b(v1[1]), f2b(v1[2]), f2b(v1[3])};
}

// merged f32->bf16 conversion of the 5 plain weight blocks
__global__ void cvtall_k(const float* __restrict__ s0, const float* __restrict__ s1,
                         const float* __restrict__ s2, const float* __restrict__ s3,
                         const float* __restrict__ s4,
                         u16* __restrict__ d0, u16* __restrict__ d1,
                         u16* __restrict__ d2, u16* __restrict__ d3,
                         u16* __restrict__ d4)
{
  const int N0 = 1179648;            // sa_inw  6*1536*512/4
  const int N1 = N0 + 393216;        // sa_outw
  const int N2 = N1 + 393216;        // ca_outw
  const int N3 = N2 + 1572864;       // ff1_w
  const int N4 = N3 + 1572864;       // ff2_w
  for (int i = blockIdx.x * 256 + threadIdx.x; i < N4; i += gridDim.x * 256) {
    const float* s; u16* d; int k;
    if (i < N0)      { s = s0; d = d0; k = i; }
    else if (i < N1) { s = s1; d = d1; k = i - N0; }
    else if (i < N2) { s = s2; d = d2; k = i - N1; }
    else if (i < N3) { s = s3; d = d3; k = i - N2; }
    else             { s = s4; d = d4; k = i - N3; }
    f4 v = ((const f4*)s)[k];
    ((u16x4*)d)[k] = (u16x4){f2b(v[0]), f2b(v[1]), f2b(v[2]), f2b(v[3])};
  }
}

__global__ void cvt_ca_v_k(const float* __restrict__ ca_inw, u16* __restrict__ dst) {
  const int i = blockIdx.x * 256 + threadIdx.x;
  if (i >= 393216) return;
  const int l = i >> 16, rem = i & 65535;
  f4 v = ((const f4*)ca_inw)[l * 196608 + 131072 + rem];
  ((u16x4*)dst)[i] = (u16x4){f2b(v[0]), f2b(v[1]), f2b(v[2]), f2b(v[3])};
}

// out_w padded to [1152][512] bf16, rows >=1027 zero
__global__ void cvt_outw_k(const float* __restrict__ out_w, u16* __restrict__ dst) {
  const int i = blockIdx.x * 256 + threadIdx.x;
  if (i >= 147456) return;
  const int row = (i * 4) >> 9;
  u16x4 o = {0, 0, 0, 0};
  if (row < 1027) {
    f4 v = ((const f4*)out_w)[i];
    o = (u16x4){f2b(v[0]), f2b(v[1]), f2b(v[2]), f2b(v[3])};
  }
  ((u16x4*)dst)[i] = o;
}

__global__ void cvt_outb_k(const float* __restrict__ out_b, float* __restrict__ dst) {
  const int i = blockIdx.x * 256 + threadIdx.x;
  if (i >= 1152) return;
  dst[i] = (i < 1027) ? out_b[i] : 0.f;
}

__global__ void cvt_memb_k(const float* __restrict__ enc, u16* __restrict__ dst) {
  const int i = blockIdx.x * 256 + threadIdx.x;
  if (i >= 32768) return;
  const int b = (i * 4) >> 9, d = (i * 4) & 511;
  f4 v = ((const f4*)enc)[(b * 8192 + d) >> 2];
  ((u16x4*)dst)[i] = (u16x4){f2b(v[0]), f2b(v[1]), f2b(v[2]), f2b(v[3])};
}

// ---------------------------------------------------------------------------
// Workspace layout (bytes)
// ---------------------------------------------------------------------------
static constexpr size_t XB_OFF    = 0;            // bf16 [15616][512]
static constexpr size_t BIG_OFF   = 15990784;     // bf16 qkv[15616][1536]/h1[15616][2048]
static constexpr size_t ATT_OFF   = 79953920;     // bf16 [15616][512]
static constexpr size_t WSA_OFF   = 95944704;     // bf16 [6][1536][512]
static constexpr size_t WSO_OFF   = 105381888;    // bf16 [6][512][512]
static constexpr size_t WCAV_OFF  = 108527616;    // bf16 [6][512][512]
static constexpr size_t WCO_OFF   = 111673344;    // bf16 [6][512][512]
static constexpr size_t WF1_OFF   = 114819072;    // bf16 [6][2048][512]
static constexpr size_t WF2_OFF   = 127401984;    // bf16 [6][512][2048]
static constexpr size_t WOUT_OFF  = 139984896;    // bf16 [1152][512]
static constexpr size_t BOUT_OFF  = 141164544;    // f32  [1152]
static constexpr size_t MEMB_OFF  = 141169152;    // bf16 [256][512]
static constexpr size_t CATMP_OFF = 141431296;    // bf16 [6][256][512]
static constexpr size_t CAVB_OFF  = 143004160;    // bf16 [6][256][512]

extern "C" void kernel_launch(void* const* d_in, const int* in_sizes, int n_in,
                              void* d_out, int out_size, void* d_ws, size_t ws_size,
                              hipStream_t stream) {
  (void)in_sizes; (void)n_in; (void)out_size; (void)ws_size;
  const float* encoder_out = (const float*)d_in[0];
  const float* point_out   = (const float*)d_in[1];
  const float* emb         = (const float*)d_in[2];
  const float* pos         = (const float*)d_in[3];
  const float* sa_inw      = (const float*)d_in[4];
  const float* sa_inb      = (const float*)d_in[5];
  const float* sa_outw     = (const float*)d_in[6];
  const float* sa_outb     = (const float*)d_in[7];
  const float* ca_inw      = (const float*)d_in[8];
  const float* ca_inb      = (const float*)d_in[9];
  const float* ca_outw     = (const float*)d_in[10];
  const float* ca_outb     = (const float*)d_in[11];
  const float* ln1_s       = (const float*)d_in[12];
  const float* ln1_b       = (const float*)d_in[13];
  const float* ln2_s       = (const float*)d_in[14];
  const float* ln2_b       = (const float*)d_in[15];
  const float* ln3_s       = (const float*)d_in[16];
  const float* ln3_b       = (const float*)d_in[17];
  const float* ff1_w       = (const float*)d_in[18];
  const float* ff1_b       = (const float*)d_in[19];
  const float* ff2_w       = (const float*)d_in[20];
  const float* ff2_b       = (const float*)d_in[21];
  const float* out_w       = (const float*)d_in[22];
  const float* out_b       = (const float*)d_in[23];
  const int*   tgt         = (const int*)d_in[24];

  char* ws = (char*)d_ws;
  u16*   XB    = (u16*)(ws + XB_OFF);
  u16*   BIG   = (u16*)(ws + BIG_OFF);
  u16*   ATT   = (u16*)(ws + ATT_OFF);
  u16*   WSA   = (u16*)(ws + WSA_OFF);
  u16*   WSO   = (u16*)(ws + WSO_OFF);
  u16*   WCAV  = (u16*)(ws + WCAV_OFF);
  u16*   WCO   = (u16*)(ws + WCO_OFF);
  u16*   WF1   = (u16*)(ws + WF1_OFF);
  u16*   WF2   = (u16*)(ws + WF2_OFF);
  u16*   WOUT  = (u16*)(ws + WOUT_OFF);
  float* BOUT  = (float*)(ws + BOUT_OFF);
  u16*   MEMB  = (u16*)(ws + MEMB_OFF);
  u16*   CATMP = (u16*)(ws + CATMP_OFF);
  u16*   CAVB  = (u16*)(ws + CAVB_OFF);

  // ---- weight conversion ----
  cvtall_k<<<dim3(2048), dim3(256), 0, stream>>>(
      sa_inw, sa_outw, ca_outw, ff1_w, ff2_w, WSA, WSO, WCO, WF1, WF2);
  cvt_ca_v_k<<<dim3(1536), dim3(256), 0, stream>>>(ca_inw, WCAV);
  cvt_outw_k<<<dim3(576), dim3(256), 0, stream>>>(out_w, WOUT);
  cvt_outb_k<<<dim3(5), dim3(256), 0, stream>>>(out_b, BOUT);
  cvt_memb_k<<<dim3(128), dim3(256), 0, stream>>>(encoder_out, MEMB);

  // ---- embedding ----
  embed_k<<<dim3(MTOT / 4), dim3(256), 0, stream>>>(emb, point_out, pos, tgt, XB);

  // ---- cross-attention vectors (x-independent), bf16 ----
  gemm_bt<64><<<dim3(4, 4, 6), dim3(256), 0, stream>>>(
      MEMB, WCAV, ca_inb + 1024, nullptr, CATMP,
      256, 512, 512, 512, 512, 0,
      0L, 262144L, 1536L, 131072L);
  gemm_bt<64><<<dim3(4, 4, 6), dim3(256), 0, stream>>>(
      CATMP, WCO, ca_outb, nullptr, CAVB,
      256, 512, 512, 512, 512, 0,
      131072L, 262144L, 512L, 131072L);

  for (int l = 0; l < 6; ++l) {
    // QKV
    gemm_bt<128><<<dim3(12, 122, 1), dim3(256), 0, stream>>>(
        XB, WSA + (long)l * 786432, sa_inb + l * 1536, nullptr, BIG,
        MTOT, 1536, 512, 1536, 1536, 0, 0L, 0L, 0L, 0L);
    // fused attention
    attn_k<<<dim3(2048), dim3(256), 0, stream>>>(BIG, tgt, ATT);
    // out-proj + resid + LN1 + CA + LN2 -> XB (fused, full-row)
    gemmln_k<true><<<dim3(244), dim3(512), 0, stream>>>(
        ATT, WSO + (long)l * 262144, sa_outb + l * 512,
        CAVB + (long)l * 131072,
        ln1_s + l * 512, ln1_b + l * 512, ln2_s + l * 512, ln2_b + l * 512,
        XB, 512);
    // FF1 + ReLU -> h1
    gemm_bt<128><<<dim3(16, 122, 1), dim3(256), 0, stream>>>(
        XB, WF1 + (long)l * 1048576, ff1_b + l * 2048, nullptr, BIG,
        MTOT, 2048, 512, 2048, 2048, 1, 0L, 0L, 0L, 0L);
    // FF2 + resid + LN3 -> XB (fused, full-row)
    gemmln_k<false><<<dim3(244), dim3(512), 0, stream>>>(
        BIG, WF2 + (long)l * 1048576, ff2_b + l * 512,
        nullptr,
        ln3_s + l * 512, ln3_b + l * 512, nullptr, nullptr,
        XB, 2048);
  }

  // ---- final logits ----
  gemm_bt<128><<<dim3(9, 122, 1), dim3(256), 0, stream>>>(
      XB, WOUT, BOUT, (float*)d_out, nullptr,
      MTOT, 1152, 512, 1027, 1027, 0, 0L, 0L, 0L, 0L);
}

// Round 7
// 1291.487 us; speedup vs baseline: 1.0088x; 1.0088x over previous
//
#include <hip/hip_runtime.h>
#include <stdint.h>
#include <stddef.h>

typedef unsigned short u16;
typedef float f4 __attribute__((ext_vector_type(4)));
typedef float f32x4 __attribute__((ext_vector_type(4)));
typedef short bf16x8 __attribute__((ext_vector_type(8)));
typedef u16 u16x4 __attribute__((ext_vector_type(4)));
typedef int i4v __attribute__((ext_vector_type(4)));

#define PAD_TOK 1026
#define LQ 61
#define NBATCH 256
#define MTOT (NBATCH * LQ)   // 15616 = 244*64 = 122*128

__device__ __forceinline__ u16 f2b(float f) {
  uint32_t x = __float_as_uint(f);
  x += 0x7fff + ((x >> 16) & 1);   // RNE
  return (u16)(x >> 16);
}
__device__ __forceinline__ float b2f(u16 u) {
  return __uint_as_float(((uint32_t)u) << 16);
}

#define GLDS(gptr, lptr) __builtin_amdgcn_global_load_lds( \
    (const __attribute__((address_space(1))) void*)(gptr), \
    (__attribute__((address_space(3))) void*)(lptr), 16, 0, 0)

__device__ __forceinline__ bf16x8 ldfrag(const u16* buf, int row, int ksl, int kg) {
  const int chunk = (ksl * 4 + kg) ^ (row & 7);
  return *(const bf16x8*)&buf[row * 64 + chunk * 8];
}

// ---------------------------------------------------------------------------
// bf16 B^T GEMM, BM x 128 tile, BK=64, 4 waves (R2-proven structure).
// ---------------------------------------------------------------------------
template<int BM>
__global__ __launch_bounds__(256) void gemm_bt(
    const u16* __restrict__ A, const u16* __restrict__ W,
    const float* __restrict__ bias,
    float* __restrict__ Cf, u16* __restrict__ Cb,
    int M, int N, int K, int Nreal, int ldc, int relu,
    long aZ, long wZ, long bZ, long cZ)
{
  constexpr int MI = BM / 32;
  const int z = blockIdx.z;
  A += z * aZ; W += z * wZ; bias += z * bZ;
  if (Cf) Cf += z * cZ;
  if (Cb) Cb += z * cZ;

  __shared__ u16 As[BM * 64];
  __shared__ u16 Bs[128 * 64];

  // bijective XCD swizzle (m204)
  const int gx = gridDim.x;
  const int nwg = gx * gridDim.y;
  const int orig = blockIdx.y * gx + blockIdx.x;
  const int q8 = nwg >> 3, r8 = nwg & 7;
  const int xcd = orig & 7, off = orig >> 3;
  const int nid = (xcd < r8 ? xcd * (q8 + 1) : r8 * (q8 + 1) + (xcd - r8) * q8) + off;
  const int bx = nid % gx, by = nid / gx;

  const int tid = threadIdx.x;
  const int wid = tid >> 6, lane = tid & 63;
  const int wr = wid >> 1, wc = wid & 1;
  const long m0 = (long)by * BM;
  const long n0 = (long)bx * 128;

  const int lr = lane >> 3;
  const int lc = lane & 7;
  const int scol = ((lc ^ lr) << 3);

  f32x4 acc[MI][4];
#pragma unroll
  for (int i = 0; i < MI; ++i)
#pragma unroll
    for (int j = 0; j < 4; ++j) acc[i][j] = (f32x4){0.f, 0.f, 0.f, 0.f};

  const u16* Abase = A + m0 * K;
  const u16* Wbase = W + n0 * K;
  const int r = lane & 15, kg = lane >> 4;

  for (int kt = 0; kt < K; kt += 64) {
#pragma unroll
    for (int c = 0; c < BM / 32; ++c) {
      const int row = wid * (BM / 4) + c * 8;
      GLDS(Abase + (long)(row + lr) * K + kt + scol, &As[row * 64]);
    }
#pragma unroll
    for (int c = 0; c < 4; ++c) {
      const int row = wid * 32 + c * 8;
      GLDS(Wbase + (long)(row + lr) * K + kt + scol, &Bs[row * 64]);
    }
    __syncthreads();

#pragma unroll
    for (int ks = 0; ks < 2; ++ks) {
      bf16x8 a[MI], b[4];
#pragma unroll
      for (int mi = 0; mi < MI; ++mi)
        a[mi] = ldfrag(As, wr * (BM / 2) + mi * 16 + r, ks, kg);
#pragma unroll
      for (int ni = 0; ni < 4; ++ni)
        b[ni] = ldfrag(Bs, wc * 64 + ni * 16 + r, ks, kg);
#pragma unroll
      for (int mi = 0; mi < MI; ++mi)
#pragma unroll
        for (int ni = 0; ni < 4; ++ni)
          acc[mi][ni] = __builtin_amdgcn_mfma_f32_16x16x32_bf16(a[mi], b[ni], acc[mi][ni], 0, 0, 0);
    }
    __syncthreads();
  }

  const int cr4 = (lane >> 4) * 4;
  const int cc = lane & 15;

  if (Cb) {
#pragma unroll
    for (int ni = 0; ni < 4; ++ni) {
      const int coll = wc * 64 + ni * 16 + cc;
      const float bv = bias[(int)n0 + coll];
#pragma unroll
      for (int mi = 0; mi < MI; ++mi) {
#pragma unroll
        for (int j = 0; j < 4; ++j) {
          const int rowl = wr * (BM / 2) + mi * 16 + cr4 + j;
          float v = acc[mi][ni][j] + bv;
          if (relu) v = fmaxf(v, 0.f);
          const int sw = (rowl & 7) << 3;
          u16* half = (coll & 64) ? Bs : As;
          half[rowl * 64 + ((coll & 63) ^ sw)] = f2b(v);
        }
      }
    }
    __syncthreads();
    constexpr int PT = BM / 16;
#pragma unroll
    for (int i = 0; i < PT; ++i) {
      const int t = i * 256 + tid;
      const int row = t >> 4, ch = t & 15;
      const int n = (int)n0 + ch * 8;
      if (n < Nreal) {
        const int phys = (ch & 7) ^ (row & 7);
        const u16* half = (ch < 8) ? As : Bs;
        bf16x8 vv = *(const bf16x8*)&half[row * 64 + phys * 8];
        *(bf16x8*)&Cb[(m0 + row) * (long)N + n] = vv;
      }
    }
  } else {
#pragma unroll
    for (int ni = 0; ni < 4; ++ni) {
      const int n = (int)n0 + wc * 64 + ni * 16 + cc;
      if (n >= Nreal) continue;
      const float bv = bias[n];
#pragma unroll
      for (int mi = 0; mi < MI; ++mi) {
#pragma unroll
        for (int j = 0; j < 4; ++j) {
          const long m = m0 + wr * (BM / 2) + mi * 16 + cr4 + j;
          float v = acc[mi][ni][j] + bv;
          if (relu) v = fmaxf(v, 0.f);
          Cf[m * ldc + n] = v;
        }
      }
    }
  }
}

// ---------------------------------------------------------------------------
// Full-row fused GEMM+LN, 2-PHASE DOUBLE-BUFFERED (T3 minimum recipe):
// BM=64, BN=512(=N), 8 waves (2M x 4N), wave 32x128.
//   CA2=true : XB = LN2( LN1(A@W^T + bias + XB) + cav )   [proj]
//   CA2=false: XB = LN1(A@W^T + bias + XB)                [FF2]
// Each iter: issue STAGE(t+1) -> ds_read+MFMA(t) -> vmcnt(0)+barrier.
// 1 block/CU (144KB LDS) but load latency now hides under compute+issue.
// 64-row tile spans up to THREE 61-row batches -> LCAV[3], sel in {0,1,2}.
// ---------------------------------------------------------------------------
template<bool CA2>
__global__ __launch_bounds__(512) void gemmln_k(
    const u16* __restrict__ A, const u16* __restrict__ W,
    const float* __restrict__ bias,
    const u16* __restrict__ cavb,
    const float* __restrict__ s1w, const float* __restrict__ b1w,
    const float* __restrict__ s2w, const float* __restrict__ b2w,
    u16* __restrict__ XB, int K)
{
  __shared__ u16 LDSBUF[2][36864];     // each: LB 512x64 (32768 u16) + LA 64x64 (4096 u16)
  __shared__ float LSTAT[64][8];
  __shared__ u16 LCAV[1536];           // cav for batches b0, b0+1, b0+2
  u16* const EP = &LDSBUF[0][0];       // epilogue reuse, row stride 516

  // m204 swizzle (gx==1)
  const int nwg = gridDim.x;
  const int orig = blockIdx.x;
  const int q8 = nwg >> 3, r8 = nwg & 7;
  const int xcd = orig & 7, off = orig >> 3;
  const int by = (xcd < r8 ? xcd * (q8 + 1) : r8 * (q8 + 1) + (xcd - r8) * q8) + off;

  const int tid = threadIdx.x;
  const int wid = tid >> 6, lane = tid & 63;
  const int wm = wid >> 2, wn = wid & 3;
  const long m0 = (long)by * 64;

  const int lr = lane >> 3, lc = lane & 7;
  const int scol = ((lc ^ lr) << 3);
  const int r = lane & 15, kg = lane >> 4;

  f32x4 acc[2][8];
#pragma unroll
  for (int i = 0; i < 2; ++i)
#pragma unroll
    for (int j = 0; j < 8; ++j) acc[i][j] = (f32x4){0.f, 0.f, 0.f, 0.f};

  const u16* Abase = A + m0 * K;

  // stage one BK=64 tile (A: 1 unit/wave, B: 8 units/wave)
#define STAGE(buf, kt) do {                                              \
    const int arow_ = wid * 8;                                           \
    GLDS(Abase + (long)(arow_ + lr) * K + (kt) + scol,                   \
         &(buf)[32768 + arow_ * 64]);                                    \
    _Pragma("unroll")                                                    \
    for (int c_ = 0; c_ < 8; ++c_) {                                     \
      const int row_ = wid * 64 + c_ * 8;                                \
      GLDS(W + (long)(row_ + lr) * K + (kt) + scol, &(buf)[row_ * 64]);  \
    }                                                                    \
  } while (0)

  const int nt = K >> 6;
  STAGE(LDSBUF[0], 0);
  asm volatile("s_waitcnt vmcnt(0)" ::: "memory");
  __builtin_amdgcn_sched_barrier(0);
  __builtin_amdgcn_s_barrier();

  for (int t = 0; t < nt; ++t) {
    u16* const bufc = &LDSBUF[t & 1][0];
    if (t + 1 < nt) STAGE(LDSBUF[(t + 1) & 1], (t + 1) << 6);
#pragma unroll
    for (int ks = 0; ks < 2; ++ks) {
      bf16x8 a0 = ldfrag(bufc + 32768, wm * 32 + r, ks, kg);
      bf16x8 a1 = ldfrag(bufc + 32768, wm * 32 + 16 + r, ks, kg);
      __builtin_amdgcn_s_setprio(1);
#pragma unroll
      for (int ni = 0; ni < 8; ++ni) {
        bf16x8 b = ldfrag(bufc, wn * 128 + ni * 16 + r, ks, kg);
        acc[0][ni] = __builtin_amdgcn_mfma_f32_16x16x32_bf16(a0, b, acc[0][ni], 0, 0, 0);
        acc[1][ni] = __builtin_amdgcn_mfma_f32_16x16x32_bf16(a1, b, acc[1][ni], 0, 0, 0);
      }
      __builtin_amdgcn_s_setprio(0);
    }
    asm volatile("s_waitcnt vmcnt(0)" ::: "memory");
    __builtin_amdgcn_sched_barrier(0);
    __builtin_amdgcn_s_barrier();
  }
#undef STAGE

  // ---------------- fused epilogue ----------------
  const int b0 = (int)(m0 / LQ);
  const int bsplit1 = (b0 + 1) * LQ;
  const int bsplit2 = (b0 + 2) * LQ;

  // stage residual XB tile (64 rows x 512) into EP, padded stride 516
#pragma unroll
  for (int i = 0; i < 8; ++i) {
    const int t = i * 512 + tid;
    const int row = t >> 6, ch = t & 63;
    *(bf16x8*)&EP[row * 516 + ch * 8] =
        *(const bf16x8*)&XB[(m0 + row) * 512 + ch * 8];
  }
  if constexpr (CA2) {
    for (int t = tid; t < 1536; t += 512) {
      const int bb = t >> 9, c = t & 511;
      int bi = b0 + bb;
      if (bi > NBATCH - 1) bi = NBATCH - 1;
      LCAV[bb * 512 + c] = cavb[(long)bi * 512 + c];
    }
  }
  __syncthreads();

  // v = acc + bias + resid
  float bcol[8];
#pragma unroll
  for (int ni = 0; ni < 8; ++ni) bcol[ni] = bias[wn * 128 + ni * 16 + r];
#pragma unroll
  for (int mi = 0; mi < 2; ++mi)
#pragma unroll
    for (int ni = 0; ni < 8; ++ni) {
      const int col = wn * 128 + ni * 16 + r;
#pragma unroll
      for (int j = 0; j < 4; ++j) {
        const int row = wm * 32 + mi * 16 + kg * 4 + j;
        acc[mi][ni][j] += bcol[ni] + b2f(EP[row * 516 + col]);
      }
    }

  // ---- stats round 1 ----
#pragma unroll
  for (int mi = 0; mi < 2; ++mi)
#pragma unroll
    for (int j = 0; j < 4; ++j) {
      float s1 = 0.f, s2 = 0.f;
#pragma unroll
      for (int ni = 0; ni < 8; ++ni) {
        const float v = acc[mi][ni][j];
        s1 += v; s2 += v * v;
      }
#pragma unroll
      for (int o = 1; o < 16; o <<= 1) {
        s1 += __shfl_xor(s1, o);
        s2 += __shfl_xor(s2, o);
      }
      if (r == 0) {
        const int row = wm * 32 + mi * 16 + kg * 4 + j;
        LSTAT[row][wn] = s1;
        LSTAT[row][4 + wn] = s2;
      }
    }
  __syncthreads();

  // ---- apply LN1 ----
  float sc[8], bc[8];
#pragma unroll
  for (int ni = 0; ni < 8; ++ni) {
    const int col = wn * 128 + ni * 16 + r;
    sc[ni] = s1w[col]; bc[ni] = b1w[col];
  }
#pragma unroll
  for (int mi = 0; mi < 2; ++mi)
#pragma unroll
    for (int j = 0; j < 4; ++j) {
      const int row = wm * 32 + mi * 16 + kg * 4 + j;
      const float S1 = LSTAT[row][0] + LSTAT[row][1] + LSTAT[row][2] + LSTAT[row][3];
      const float S2 = LSTAT[row][4] + LSTAT[row][5] + LSTAT[row][6] + LSTAT[row][7];
      const float mean = S1 * (1.f / 512.f);
      const float var = S2 * (1.f / 512.f) - mean * mean;
      const float rstd = rsqrtf(var + 1e-5f);
#pragma unroll
      for (int ni = 0; ni < 8; ++ni)
        acc[mi][ni][j] = (acc[mi][ni][j] - mean) * rstd * sc[ni] + bc[ni];
    }

  if constexpr (CA2) {
    // + cav (3-batch-aware select), then LN2
#pragma unroll
    for (int mi = 0; mi < 2; ++mi)
#pragma unroll
      for (int j = 0; j < 4; ++j) {
        const int row = wm * 32 + mi * 16 + kg * 4 + j;
        const int gr = (int)m0 + row;
        const int sel = (gr >= bsplit2) ? 2 : ((gr >= bsplit1) ? 1 : 0);
#pragma unroll
        for (int ni = 0; ni < 8; ++ni) {
          const int col = wn * 128 + ni * 16 + r;
          acc[mi][ni][j] += b2f(LCAV[sel * 512 + col]);
        }
      }
    __syncthreads();   // everyone done reading round-1 LSTAT
#pragma unroll
    for (int mi = 0; mi < 2; ++mi)
#pragma unroll
      for (int j = 0; j < 4; ++j) {
        float s1 = 0.f, s2 = 0.f;
#pragma unroll
        for (int ni = 0; ni < 8; ++ni) {
          const float v = acc[mi][ni][j];
          s1 += v; s2 += v * v;
        }
#pragma unroll
        for (int o = 1; o < 16; o <<= 1) {
          s1 += __shfl_xor(s1, o);
          s2 += __shfl_xor(s2, o);
        }
        if (r == 0) {
          const int row = wm * 32 + mi * 16 + kg * 4 + j;
          LSTAT[row][wn] = s1;
          LSTAT[row][4 + wn] = s2;
        }
      }
    __syncthreads();
#pragma unroll
    for (int ni = 0; ni < 8; ++ni) {
      const int col = wn * 128 + ni * 16 + r;
      sc[ni] = s2w[col]; bc[ni] = b2w[col];
    }
#pragma unroll
    for (int mi = 0; mi < 2; ++mi)
#pragma unroll
      for (int j = 0; j < 4; ++j) {
        const int row = wm * 32 + mi * 16 + kg * 4 + j;
        const float S1 = LSTAT[row][0] + LSTAT[row][1] + LSTAT[row][2] + LSTAT[row][3];
        const float S2 = LSTAT[row][4] + LSTAT[row][5] + LSTAT[row][6] + LSTAT[row][7];
        const float mean = S1 * (1.f / 512.f);
        const float var = S2 * (1.f / 512.f) - mean * mean;
        const float rstd = rsqrtf(var + 1e-5f);
#pragma unroll
        for (int ni = 0; ni < 8; ++ni)
          acc[mi][ni][j] = (acc[mi][ni][j] - mean) * rstd * sc[ni] + bc[ni];
      }
  }

  // write bf16 to EP, then coalesced store to XB
#pragma unroll
  for (int mi = 0; mi < 2; ++mi)
#pragma unroll
    for (int ni = 0; ni < 8; ++ni) {
      const int col = wn * 128 + ni * 16 + r;
#pragma unroll
      for (int j = 0; j < 4; ++j) {
        const int row = wm * 32 + mi * 16 + kg * 4 + j;
        EP[row * 516 + col] = f2b(acc[mi][ni][j]);
      }
    }
  __syncthreads();
#pragma unroll
  for (int i = 0; i < 8; ++i) {
    const int t = i * 512 + tid;
    const int row = t >> 6, ch = t & 63;
    *(bf16x8*)&XB[(m0 + row) * 512 + ch * 8] =
        *(const bf16x8*)&EP[row * 516 + ch * 8];
  }
}

// ---------------------------------------------------------------------------
// Fused self-attention: one block per (batch, head).
// ---------------------------------------------------------------------------
__global__ __launch_bounds__(256) void attn_k(const u16* __restrict__ qkv,
                                              const int* __restrict__ tgt,
                                              u16* __restrict__ outp)
{
  __shared__ u16 Qs[64 * 72];
  __shared__ u16 Ks[64 * 72];
  __shared__ u16 Vt[64 * 72];
  __shared__ float S[64 * 65];
  __shared__ int stok[64];

  const int bid = blockIdx.x;
  const int b = bid >> 3, h = bid & 7;
  const int tid = threadIdx.x;
  const int tr = tid >> 2, seg = tid & 3;

  if (tid < 64) stok[tid] = (tid < 61) ? tgt[b * 62 + tid] : -1;

  const long rowbase = ((long)(b * LQ + tr)) * 1536 + h * 64;
  if (tr < LQ) {
    const i4v* qsrc = (const i4v*)(qkv + rowbase + seg * 16);
    i4v q0 = qsrc[0], q1 = qsrc[1];
    *(i4v*)&Qs[tr * 72 + seg * 16] = q0;
    *(i4v*)&Qs[tr * 72 + seg * 16 + 8] = q1;
    const i4v* ksrc = (const i4v*)(qkv + rowbase + 512 + seg * 16);
    i4v k0 = ksrc[0], k1 = ksrc[1];
    *(i4v*)&Ks[tr * 72 + seg * 16] = k0;
    *(i4v*)&Ks[tr * 72 + seg * 16 + 8] = k1;
    const u16* vsrc = qkv + rowbase + 1024 + seg * 16;
#pragma unroll
    for (int i = 0; i < 16; ++i) Vt[(seg * 16 + i) * 72 + tr] = vsrc[i];
  } else {
    i4v zz = {0, 0, 0, 0};
    *(i4v*)&Qs[tr * 72 + seg * 16] = zz;
    *(i4v*)&Qs[tr * 72 + seg * 16 + 8] = zz;
    *(i4v*)&Ks[tr * 72 + seg * 16] = zz;
    *(i4v*)&Ks[tr * 72 + seg * 16 + 8] = zz;
#pragma unroll
    for (int i = 0; i < 16; ++i) Vt[(seg * 16 + i) * 72 + tr] = 0;
  }
  __syncthreads();

  const int lane = tid & 63, w = tid >> 6;
  const int r = lane & 15, kg = lane >> 4;

  {   // QK^T
    f32x4 s[4];
#pragma unroll
    for (int ni = 0; ni < 4; ++ni) s[ni] = (f32x4){0.f, 0.f, 0.f, 0.f};
    bf16x8 a0 = *(const bf16x8*)&Qs[(w * 16 + r) * 72 + kg * 8];
    bf16x8 a1 = *(const bf16x8*)&Qs[(w * 16 + r) * 72 + 32 + kg * 8];
#pragma unroll
    for (int ni = 0; ni < 4; ++ni) {
      bf16x8 b0 = *(const bf16x8*)&Ks[(ni * 16 + r) * 72 + kg * 8];
      bf16x8 b1 = *(const bf16x8*)&Ks[(ni * 16 + r) * 72 + 32 + kg * 8];
      s[ni] = __builtin_amdgcn_mfma_f32_16x16x32_bf16(a0, b0, s[ni], 0, 0, 0);
      s[ni] = __builtin_amdgcn_mfma_f32_16x16x32_bf16(a1, b1, s[ni], 0, 0, 0);
    }
#pragma unroll
    for (int ni = 0; ni < 4; ++ni)
#pragma unroll
      for (int j = 0; j < 4; ++j)
        S[(w * 16 + kg * 4 + j) * 65 + ni * 16 + r] = s[ni][j];
  }
  __syncthreads();

  {   // masked softmax
    const int row = tid >> 2, g = tid & 3;
    float vals[16];
    float mx = -3e38f;
#pragma unroll
    for (int i = 0; i < 16; ++i) {
      const int k = g * 16 + i;
      float v = S[row * 65 + k] * 0.125f;
      const bool ok = (k <= row) && (k < LQ) && (stok[k] != PAD_TOK);
      v = ok ? v : -1e30f;
      vals[i] = v;
      mx = fmaxf(mx, v);
    }
    mx = fmaxf(mx, __shfl_xor(mx, 1));
    mx = fmaxf(mx, __shfl_xor(mx, 2));
    float sum = 0.f;
#pragma unroll
    for (int i = 0; i < 16; ++i) { float e = __expf(vals[i] - mx); vals[i] = e; sum += e; }
    sum += __shfl_xor(sum, 1);
    sum += __shfl_xor(sum, 2);
    const float inv = 1.f / sum;
#pragma unroll
    for (int i = 0; i < 16; ++i) Qs[row * 72 + g * 16 + i] = f2b(vals[i] * inv);
  }
  __syncthreads();

  {   // PV, swizzled bounce into Ks
    f32x4 o[4];
#pragma unroll
    for (int ni = 0; ni < 4; ++ni) o[ni] = (f32x4){0.f, 0.f, 0.f, 0.f};
    bf16x8 a0 = *(const bf16x8*)&Qs[(w * 16 + r) * 72 + kg * 8];
    bf16x8 a1 = *(const bf16x8*)&Qs[(w * 16 + r) * 72 + 32 + kg * 8];
#pragma unroll
    for (int ni = 0; ni < 4; ++ni) {
      bf16x8 b0 = *(const bf16x8*)&Vt[(ni * 16 + r) * 72 + kg * 8];
      bf16x8 b1 = *(const bf16x8*)&Vt[(ni * 16 + r) * 72 + 32 + kg * 8];
      o[ni] = __builtin_amdgcn_mfma_f32_16x16x32_bf16(a0, b0, o[ni], 0, 0, 0);
      o[ni] = __builtin_amdgcn_mfma_f32_16x16x32_bf16(a1, b1, o[ni], 0, 0, 0);
    }
#pragma unroll
    for (int ni = 0; ni < 4; ++ni)
#pragma unroll
      for (int j = 0; j < 4; ++j) {
        const int qrow = w * 16 + kg * 4 + j;
        const int col = ni * 16 + r;
        Ks[qrow * 64 + (col ^ ((qrow & 7) << 3))] = f2b(o[ni][j]);
      }
  }
  __syncthreads();

  {   // coalesced O store
    const int row = tid >> 2, sub = tid & 3;
    if (row < LQ) {
      const long obase = ((long)(b * LQ + row)) * 512 + h * 64;
#pragma unroll
      for (int i = 0; i < 2; ++i) {
        const int ch = i * 4 + sub;
        const int phys = ch ^ (row & 7);
        bf16x8 vv = *(const bf16x8*)&Ks[row * 64 + phys * 8];
        *(bf16x8*)&outp[obase + ch * 8] = vv;
      }
    }
  }
}

// Embedding: xb[m] = bf16(emb[tok] + point_out[b] + pos_embed[t])
__global__ __launch_bounds__(256) void embed_k(const float* __restrict__ emb,
                                               const float* __restrict__ pout,
                                               const float* __restrict__ pos,
                                               const int* __restrict__ tgt,
                                               u16* __restrict__ XB)
{
  const int m = blockIdx.x * 4 + (threadIdx.x >> 6);
  const int lane = threadIdx.x & 63;
  const int b = m / LQ, t = m % LQ;
  const int tok = tgt[b * 62 + t];
  const int d0 = lane * 8;
  const f4* e = (const f4*)(emb + (long)tok * 512 + d0);
  const f4* p = (const f4*)(pout + (long)b * 512 + d0);
  const f4* q = (const f4*)(pos + (long)t * 512 + d0);
  f4 v0 = e[0] + p[0] + q[0];
  f4 v1 = e[1] + p[1] + q[1];
  u16x4* xb = (u16x4*)(XB + (long)m * 512 + d0);
  xb[0] = (u16x4){f2b(v0[0]), f2b(v0[1]), f2b(v0[2]), f2b(v0[3])};
  xb[1] = (u16x4){f2b(v1[0]), f2b(v1[1]), f2b(v1[2]), f2b(v1[3])};
}

// merged f32->bf16 conversion of the 5 plain weight blocks
__global__ void cvtall_k(const float* __restrict__ s0, const float* __restrict__ s1,
                         const float* __restrict__ s2, const float* __restrict__ s3,
                         const float* __restrict__ s4,
                         u16* __restrict__ d0, u16* __restrict__ d1,
                         u16* __restrict__ d2, u16* __restrict__ d3,
                         u16* __restrict__ d4)
{
  const int N0 = 1179648;            // sa_inw  6*1536*512/4
  const int N1 = N0 + 393216;        // sa_outw
  const int N2 = N1 + 393216;        // ca_outw
  const int N3 = N2 + 1572864;       // ff1_w
  const int N4 = N3 + 1572864;       // ff2_w
  for (int i = blockIdx.x * 256 + threadIdx.x; i < N4; i += gridDim.x * 256) {
    const float* s; u16* d; int k;
    if (i < N0)      { s = s0; d = d0; k = i; }
    else if (i < N1) { s = s1; d = d1; k = i - N0; }
    else if (i < N2) { s = s2; d = d2; k = i - N1; }
    else if (i < N3) { s = s3; d = d3; k = i - N2; }
    else             { s = s4; d = d4; k = i - N3; }
    f4 v = ((const f4*)s)[k];
    ((u16x4*)d)[k] = (u16x4){f2b(v[0]), f2b(v[1]), f2b(v[2]), f2b(v[3])};
  }
}

__global__ void cvt_ca_v_k(const float* __restrict__ ca_inw, u16* __restrict__ dst) {
  const int i = blockIdx.x * 256 + threadIdx.x;
  if (i >= 393216) return;
  const int l = i >> 16, rem = i & 65535;
  f4 v = ((const f4*)ca_inw)[l * 196608 + 131072 + rem];
  ((u16x4*)dst)[i] = (u16x4){f2b(v[0]), f2b(v[1]), f2b(v[2]), f2b(v[3])};
}

// out_w padded to [1152][512] bf16, rows >=1027 zero
__global__ void cvt_outw_k(const float* __restrict__ out_w, u16* __restrict__ dst) {
  const int i = blockIdx.x * 256 + threadIdx.x;
  if (i >= 147456) return;
  const int row = (i * 4) >> 9;
  u16x4 o = {0, 0, 0, 0};
  if (row < 1027) {
    f4 v = ((const f4*)out_w)[i];
    o = (u16x4){f2b(v[0]), f2b(v[1]), f2b(v[2]), f2b(v[3])};
  }
  ((u16x4*)dst)[i] = o;
}

__global__ void cvt_outb_k(const float* __restrict__ out_b, float* __restrict__ dst) {
  const int i = blockIdx.x * 256 + threadIdx.x;
  if (i >= 1152) return;
  dst[i] = (i < 1027) ? out_b[i] : 0.f;
}

__global__ void cvt_memb_k(const float* __restrict__ enc, u16* __restrict__ dst) {
  const int i = blockIdx.x * 256 + threadIdx.x;
  if (i >= 32768) return;
  const int b = (i * 4) >> 9, d = (i * 4) & 511;
  f4 v = ((const f4*)enc)[(b * 8192 + d) >> 2];
  ((u16x4*)dst)[i] = (u16x4){f2b(v[0]), f2b(v[1]), f2b(v[2]), f2b(v[3])};
}

// ---------------------------------------------------------------------------
// Workspace layout (bytes)
// ---------------------------------------------------------------------------
static constexpr size_t XB_OFF    = 0;            // bf16 [15616][512]
static constexpr size_t BIG_OFF   = 15990784;     // bf16 qkv[15616][1536]/h1[15616][2048]
static constexpr size_t ATT_OFF   = 79953920;     // bf16 [15616][512]
static constexpr size_t WSA_OFF   = 95944704;     // bf16 [6][1536][512]
static constexpr size_t WSO_OFF   = 105381888;    // bf16 [6][512][512]
static constexpr size_t WCAV_OFF  = 108527616;    // bf16 [6][512][512]
static constexpr size_t WCO_OFF   = 111673344;    // bf16 [6][512][512]
static constexpr size_t WF1_OFF   = 114819072;    // bf16 [6][2048][512]
static constexpr size_t WF2_OFF   = 127401984;    // bf16 [6][512][2048]
static constexpr size_t WOUT_OFF  = 139984896;    // bf16 [1152][512]
static constexpr size_t BOUT_OFF  = 141164544;    // f32  [1152]
static constexpr size_t MEMB_OFF  = 141169152;    // bf16 [256][512]
static constexpr size_t CATMP_OFF = 141431296;    // bf16 [6][256][512]
static constexpr size_t CAVB_OFF  = 143004160;    // bf16 [6][256][512]

extern "C" void kernel_launch(void* const* d_in, const int* in_sizes, int n_in,
                              void* d_out, int out_size, void* d_ws, size_t ws_size,
                              hipStream_t stream) {
  (void)in_sizes; (void)n_in; (void)out_size; (void)ws_size;
  const float* encoder_out = (const float*)d_in[0];
  const float* point_out   = (const float*)d_in[1];
  const float* emb         = (const float*)d_in[2];
  const float* pos         = (const float*)d_in[3];
  const float* sa_inw      = (const float*)d_in[4];
  const float* sa_inb      = (const float*)d_in[5];
  const float* sa_outw     = (const float*)d_in[6];
  const float* sa_outb     = (const float*)d_in[7];
  const float* ca_inw      = (const float*)d_in[8];
  const float* ca_inb      = (const float*)d_in[9];
  const float* ca_outw     = (const float*)d_in[10];
  const float* ca_outb     = (const float*)d_in[11];
  const float* ln1_s       = (const float*)d_in[12];
  const float* ln1_b       = (const float*)d_in[13];
  const float* ln2_s       = (const float*)d_in[14];
  const float* ln2_b       = (const float*)d_in[15];
  const float* ln3_s       = (const float*)d_in[16];
  const float* ln3_b       = (const float*)d_in[17];
  const float* ff1_w       = (const float*)d_in[18];
  const float* ff1_b       = (const float*)d_in[19];
  const float* ff2_w       = (const float*)d_in[20];
  const float* ff2_b       = (const float*)d_in[21];
  const float* out_w       = (const float*)d_in[22];
  const float* out_b       = (const float*)d_in[23];
  const int*   tgt         = (const int*)d_in[24];

  char* ws = (char*)d_ws;
  u16*   XB    = (u16*)(ws + XB_OFF);
  u16*   BIG   = (u16*)(ws + BIG_OFF);
  u16*   ATT   = (u16*)(ws + ATT_OFF);
  u16*   WSA   = (u16*)(ws + WSA_OFF);
  u16*   WSO   = (u16*)(ws + WSO_OFF);
  u16*   WCAV  = (u16*)(ws + WCAV_OFF);
  u16*   WCO   = (u16*)(ws + WCO_OFF);
  u16*   WF1   = (u16*)(ws + WF1_OFF);
  u16*   WF2   = (u16*)(ws + WF2_OFF);
  u16*   WOUT  = (u16*)(ws + WOUT_OFF);
  float* BOUT  = (float*)(ws + BOUT_OFF);
  u16*   MEMB  = (u16*)(ws + MEMB_OFF);
  u16*   CATMP = (u16*)(ws + CATMP_OFF);
  u16*   CAVB  = (u16*)(ws + CAVB_OFF);

  // ---- weight conversion ----
  cvtall_k<<<dim3(2048), dim3(256), 0, stream>>>(
      sa_inw, sa_outw, ca_outw, ff1_w, ff2_w, WSA, WSO, WCO, WF1, WF2);
  cvt_ca_v_k<<<dim3(1536), dim3(256), 0, stream>>>(ca_inw, WCAV);
  cvt_outw_k<<<dim3(576), dim3(256), 0, stream>>>(out_w, WOUT);
  cvt_outb_k<<<dim3(5), dim3(256), 0, stream>>>(out_b, BOUT);
  cvt_memb_k<<<dim3(128), dim3(256), 0, stream>>>(encoder_out, MEMB);

  // ---- embedding ----
  embed_k<<<dim3(MTOT / 4), dim3(256), 0, stream>>>(emb, point_out, pos, tgt, XB);

  // ---- cross-attention vectors (x-independent), bf16 ----
  gemm_bt<64><<<dim3(4, 4, 6), dim3(256), 0, stream>>>(
      MEMB, WCAV, ca_inb + 1024, nullptr, CATMP,
      256, 512, 512, 512, 512, 0,
      0L, 262144L, 1536L, 131072L);
  gemm_bt<64><<<dim3(4, 4, 6), dim3(256), 0, stream>>>(
      CATMP, WCO, ca_outb, nullptr, CAVB,
      256, 512, 512, 512, 512, 0,
      131072L, 262144L, 512L, 131072L);

  for (int l = 0; l < 6; ++l) {
    // QKV
    gemm_bt<128><<<dim3(12, 122, 1), dim3(256), 0, stream>>>(
        XB, WSA + (long)l * 786432, sa_inb + l * 1536, nullptr, BIG,
        MTOT, 1536, 512, 1536, 1536, 0, 0L, 0L, 0L, 0L);
    // fused attention
    attn_k<<<dim3(2048), dim3(256), 0, stream>>>(BIG, tgt, ATT);
    // out-proj + resid + LN1 + CA + LN2 -> XB (fused, full-row, 2-phase)
    gemmln_k<true><<<dim3(244), dim3(512), 0, stream>>>(
        ATT, WSO + (long)l * 262144, sa_outb + l * 512,
        CAVB + (long)l * 131072,
        ln1_s + l * 512, ln1_b + l * 512, ln2_s + l * 512, ln2_b + l * 512,
        XB, 512);
    // FF1 + ReLU -> h1
    gemm_bt<128><<<dim3(16, 122, 1), dim3(256), 0, stream>>>(
        XB, WF1 + (long)l * 1048576, ff1_b + l * 2048, nullptr, BIG,
        MTOT, 2048, 512, 2048, 2048, 1, 0L, 0L, 0L, 0L);
    // FF2 + resid + LN3 -> XB (fused, full-row, 2-phase)
    gemmln_k<false><<<dim3(244), dim3(512), 0, stream>>>(
        BIG, WF2 + (long)l * 1048576, ff2_b + l * 512,
        nullptr,
        ln3_s + l * 512, ln3_b + l * 512, nullptr, nullptr,
        XB, 2048);
  }

  // ---- final logits ----
  gemm_bt<128><<<dim3(9, 122, 1), dim3(256), 0, stream>>>(
      XB, WOUT, BOUT, (float*)d_out, nullptr,
      MTOT, 1152, 512, 1027, 1027, 0, 0L, 0L, 0L, 0L);
}

// Round 8
// 1123.807 us; speedup vs baseline: 1.1593x; 1.1492x over previous
//
#include <hip/hip_runtime.h>
#include <stdint.h>
#include <stddef.h>

typedef unsigned short u16;
typedef float f4 __attribute__((ext_vector_type(4)));
typedef float f32x4 __attribute__((ext_vector_type(4)));
typedef short bf16x8 __attribute__((ext_vector_type(8)));
typedef u16 u16x4 __attribute__((ext_vector_type(4)));
typedef int i4v __attribute__((ext_vector_type(4)));

#define PAD_TOK 1026
#define LQ 61
#define NBATCH 256
#define MTOT (NBATCH * LQ)   // 15616 = 244*64 = 122*128

__device__ __forceinline__ u16 f2b(float f) {
  uint32_t x = __float_as_uint(f);
  x += 0x7fff + ((x >> 16) & 1);   // RNE
  return (u16)(x >> 16);
}
__device__ __forceinline__ float b2f(u16 u) {
  return __uint_as_float(((uint32_t)u) << 16);
}

#define GLDS(gptr, lptr) __builtin_amdgcn_global_load_lds( \
    (const __attribute__((address_space(1))) void*)(gptr), \
    (__attribute__((address_space(3))) void*)(lptr), 16, 0, 0)

__device__ __forceinline__ bf16x8 ldfrag(const u16* buf, int row, int ksl, int kg) {
  const int chunk = (ksl * 4 + kg) ^ (row & 7);
  return *(const bf16x8*)&buf[row * 64 + chunk * 8];
}

// ---------------------------------------------------------------------------
// 128x256 bf16 B^T GEMM, BK=64, 512 threads (8 waves, 2M x 4N, wave 64x64).
// Higher MFMA-per-staged-byte than 128x128 (48KB/block at 2x MFMA).
// bf16 out via two-half LDS bounce (conflict-free XOR, 512B coalesced stores).
// ---------------------------------------------------------------------------
__global__ __launch_bounds__(512) void gemm_bt2(
    const u16* __restrict__ A, const u16* __restrict__ W,
    const float* __restrict__ bias,
    float* __restrict__ Cf, u16* __restrict__ Cb,
    int N, int K, int Nreal, int ldc, int relu)
{
  __shared__ u16 SH[384 * 64];         // As 128x64 | Bs 256x64 ; bounce: 64x256
  u16* const As = SH;
  u16* const Bs = SH + 8192;

  // bijective XCD swizzle (m204)
  const int gx = gridDim.x;
  const int nwg = gx * gridDim.y;
  const int orig = blockIdx.y * gx + blockIdx.x;
  const int q8 = nwg >> 3, r8 = nwg & 7;
  const int xcd = orig & 7, off = orig >> 3;
  const int nid = (xcd < r8 ? xcd * (q8 + 1) : r8 * (q8 + 1) + (xcd - r8) * q8) + off;
  const int bx = nid % gx, by = nid / gx;

  const int tid = threadIdx.x;
  const int wid = tid >> 6, lane = tid & 63;
  const int wm = wid >> 2, wn = wid & 3;
  const long m0 = (long)by * 128;
  const long n0 = (long)bx * 256;

  const int lr = lane >> 3;
  const int lc = lane & 7;
  const int scol = ((lc ^ lr) << 3);

  f32x4 acc[4][4];
#pragma unroll
  for (int i = 0; i < 4; ++i)
#pragma unroll
    for (int j = 0; j < 4; ++j) acc[i][j] = (f32x4){0.f, 0.f, 0.f, 0.f};

  const u16* Abase = A + m0 * K;
  const u16* Wbase = W + n0 * K;
  const int r = lane & 15, kg = lane >> 4;

  for (int kt = 0; kt < K; kt += 64) {
#pragma unroll
    for (int c = 0; c < 2; ++c) {        // A: 128 rows, 16/wave
      const int row = wid * 16 + c * 8;
      GLDS(Abase + (long)(row + lr) * K + kt + scol, &As[row * 64]);
    }
#pragma unroll
    for (int c = 0; c < 4; ++c) {        // B: 256 rows, 32/wave
      const int row = wid * 32 + c * 8;
      GLDS(Wbase + (long)(row + lr) * K + kt + scol, &Bs[row * 64]);
    }
    __syncthreads();

#pragma unroll
    for (int ks = 0; ks < 2; ++ks) {
      bf16x8 a[4], b[4];
#pragma unroll
      for (int mi = 0; mi < 4; ++mi)
        a[mi] = ldfrag(As, wm * 64 + mi * 16 + r, ks, kg);
#pragma unroll
      for (int ni = 0; ni < 4; ++ni)
        b[ni] = ldfrag(Bs, wn * 64 + ni * 16 + r, ks, kg);
#pragma unroll
      for (int mi = 0; mi < 4; ++mi)
#pragma unroll
        for (int ni = 0; ni < 4; ++ni)
          acc[mi][ni] = __builtin_amdgcn_mfma_f32_16x16x32_bf16(a[mi], b[ni], acc[mi][ni], 0, 0, 0);
    }
    __syncthreads();
  }

  const int cr4 = (lane >> 4) * 4;
  const int cc = lane & 15;

  if (Cb) {
    // two half-passes (rows 0..63 by wm=0 waves, 64..127 by wm=1)
#pragma unroll
    for (int half = 0; half < 2; ++half) {
      if (wm == half) {
#pragma unroll
        for (int ni = 0; ni < 4; ++ni) {
          const int coll = wn * 64 + ni * 16 + cc;        // 0..255
          const float bv = bias[(int)n0 + coll];
#pragma unroll
          for (int mi = 0; mi < 4; ++mi) {
#pragma unroll
            for (int j = 0; j < 4; ++j) {
              const int rowl = mi * 16 + cr4 + j;         // 0..63
              float v = acc[mi][ni][j] + bv;
              if (relu) v = fmaxf(v, 0.f);
              const int phys = (coll >> 3) ^ (rowl & 31);
              SH[rowl * 256 + phys * 8 + (coll & 7)] = f2b(v);
            }
          }
        }
      }
      __syncthreads();
#pragma unroll
      for (int i = 0; i < 4; ++i) {
        const int t = i * 512 + tid;
        const int row = t >> 5, ch = t & 31;
        const int n = (int)n0 + ch * 8;
        if (n < Nreal) {
          const int phys = ch ^ (row & 31);
          *(bf16x8*)&Cb[(m0 + half * 64 + row) * (long)N + n] =
              *(const bf16x8*)&SH[row * 256 + phys * 8];
        }
      }
      __syncthreads();
    }
  } else {
#pragma unroll
    for (int ni = 0; ni < 4; ++ni) {
      const int n = (int)n0 + wn * 64 + ni * 16 + cc;
      if (n >= Nreal) continue;
      const float bv = bias[n];
#pragma unroll
      for (int mi = 0; mi < 4; ++mi) {
#pragma unroll
        for (int j = 0; j < 4; ++j) {
          const long m = m0 + wm * 64 + mi * 16 + cr4 + j;
          float v = acc[mi][ni][j] + bv;
          if (relu) v = fmaxf(v, 0.f);
          Cf[m * ldc + n] = v;
        }
      }
    }
  }
}

// ---------------------------------------------------------------------------
// bf16 B^T GEMM, BM x 128 tile, BK=64, 4 waves (R2-proven structure).
// ---------------------------------------------------------------------------
template<int BM>
__global__ __launch_bounds__(256) void gemm_bt(
    const u16* __restrict__ A, const u16* __restrict__ W,
    const float* __restrict__ bias,
    float* __restrict__ Cf, u16* __restrict__ Cb,
    int M, int N, int K, int Nreal, int ldc, int relu,
    long aZ, long wZ, long bZ, long cZ)
{
  constexpr int MI = BM / 32;
  const int z = blockIdx.z;
  A += z * aZ; W += z * wZ; bias += z * bZ;
  if (Cf) Cf += z * cZ;
  if (Cb) Cb += z * cZ;

  __shared__ u16 As[BM * 64];
  __shared__ u16 Bs[128 * 64];

  const int gx = gridDim.x;
  const int nwg = gx * gridDim.y;
  const int orig = blockIdx.y * gx + blockIdx.x;
  const int q8 = nwg >> 3, r8 = nwg & 7;
  const int xcd = orig & 7, off = orig >> 3;
  const int nid = (xcd < r8 ? xcd * (q8 + 1) : r8 * (q8 + 1) + (xcd - r8) * q8) + off;
  const int bx = nid % gx, by = nid / gx;

  const int tid = threadIdx.x;
  const int wid = tid >> 6, lane = tid & 63;
  const int wr = wid >> 1, wc = wid & 1;
  const long m0 = (long)by * BM;
  const long n0 = (long)bx * 128;

  const int lr = lane >> 3;
  const int lc = lane & 7;
  const int scol = ((lc ^ lr) << 3);

  f32x4 acc[MI][4];
#pragma unroll
  for (int i = 0; i < MI; ++i)
#pragma unroll
    for (int j = 0; j < 4; ++j) acc[i][j] = (f32x4){0.f, 0.f, 0.f, 0.f};

  const u16* Abase = A + m0 * K;
  const u16* Wbase = W + n0 * K;
  const int r = lane & 15, kg = lane >> 4;

  for (int kt = 0; kt < K; kt += 64) {
#pragma unroll
    for (int c = 0; c < BM / 32; ++c) {
      const int row = wid * (BM / 4) + c * 8;
      GLDS(Abase + (long)(row + lr) * K + kt + scol, &As[row * 64]);
    }
#pragma unroll
    for (int c = 0; c < 4; ++c) {
      const int row = wid * 32 + c * 8;
      GLDS(Wbase + (long)(row + lr) * K + kt + scol, &Bs[row * 64]);
    }
    __syncthreads();

#pragma unroll
    for (int ks = 0; ks < 2; ++ks) {
      bf16x8 a[MI], b[4];
#pragma unroll
      for (int mi = 0; mi < MI; ++mi)
        a[mi] = ldfrag(As, wr * (BM / 2) + mi * 16 + r, ks, kg);
#pragma unroll
      for (int ni = 0; ni < 4; ++ni)
        b[ni] = ldfrag(Bs, wc * 64 + ni * 16 + r, ks, kg);
#pragma unroll
      for (int mi = 0; mi < MI; ++mi)
#pragma unroll
        for (int ni = 0; ni < 4; ++ni)
          acc[mi][ni] = __builtin_amdgcn_mfma_f32_16x16x32_bf16(a[mi], b[ni], acc[mi][ni], 0, 0, 0);
    }
    __syncthreads();
  }

  const int cr4 = (lane >> 4) * 4;
  const int cc = lane & 15;

  if (Cb) {
#pragma unroll
    for (int ni = 0; ni < 4; ++ni) {
      const int coll = wc * 64 + ni * 16 + cc;
      const float bv = bias[(int)n0 + coll];
#pragma unroll
      for (int mi = 0; mi < MI; ++mi) {
#pragma unroll
        for (int j = 0; j < 4; ++j) {
          const int rowl = wr * (BM / 2) + mi * 16 + cr4 + j;
          float v = acc[mi][ni][j] + bv;
          if (relu) v = fmaxf(v, 0.f);
          const int sw = (rowl & 7) << 3;
          u16* half = (coll & 64) ? Bs : As;
          half[rowl * 64 + ((coll & 63) ^ sw)] = f2b(v);
        }
      }
    }
    __syncthreads();
    constexpr int PT = BM / 16;
#pragma unroll
    for (int i = 0; i < PT; ++i) {
      const int t = i * 256 + tid;
      const int row = t >> 4, ch = t & 15;
      const int n = (int)n0 + ch * 8;
      if (n < Nreal) {
        const int phys = (ch & 7) ^ (row & 7);
        const u16* half = (ch < 8) ? As : Bs;
        bf16x8 vv = *(const bf16x8*)&half[row * 64 + phys * 8];
        *(bf16x8*)&Cb[(m0 + row) * (long)N + n] = vv;
      }
    }
  } else {
#pragma unroll
    for (int ni = 0; ni < 4; ++ni) {
      const int n = (int)n0 + wc * 64 + ni * 16 + cc;
      if (n >= Nreal) continue;
      const float bv = bias[n];
#pragma unroll
      for (int mi = 0; mi < MI; ++mi) {
#pragma unroll
        for (int j = 0; j < 4; ++j) {
          const long m = m0 + wr * (BM / 2) + mi * 16 + cr4 + j;
          float v = acc[mi][ni][j] + bv;
          if (relu) v = fmaxf(v, 0.f);
          Cf[m * ldc + n] = v;
        }
      }
    }
  }
}

// ---------------------------------------------------------------------------
// Full-row fused GEMM+LN (proj only, K=512): BM=64, BN=512, 8 waves.
// XB = LN2( LN1(A@W^T + bias + XB) + cav ). 64-row tile spans up to THREE
// 61-row batches -> LCAV[3], sel in {0,1,2}. 2-phase dbuf staging.
// ---------------------------------------------------------------------------
__global__ __launch_bounds__(512) void gemmln_k(
    const u16* __restrict__ A, const u16* __restrict__ W,
    const float* __restrict__ bias,
    const u16* __restrict__ cavb,
    const float* __restrict__ s1w, const float* __restrict__ b1w,
    const float* __restrict__ s2w, const float* __restrict__ b2w,
    u16* __restrict__ XB, int K)
{
  __shared__ u16 LDSBUF[2][36864];
  __shared__ float LSTAT[64][8];
  __shared__ u16 LCAV[1536];
  u16* const EP = &LDSBUF[0][0];       // epilogue reuse, row stride 516

  const int nwg = gridDim.x;
  const int orig = blockIdx.x;
  const int q8 = nwg >> 3, r8 = nwg & 7;
  const int xcd = orig & 7, off = orig >> 3;
  const int by = (xcd < r8 ? xcd * (q8 + 1) : r8 * (q8 + 1) + (xcd - r8) * q8) + off;

  const int tid = threadIdx.x;
  const int wid = tid >> 6, lane = tid & 63;
  const int wm = wid >> 2, wn = wid & 3;
  const long m0 = (long)by * 64;

  const int lr = lane >> 3, lc = lane & 7;
  const int scol = ((lc ^ lr) << 3);
  const int r = lane & 15, kg = lane >> 4;

  f32x4 acc[2][8];
#pragma unroll
  for (int i = 0; i < 2; ++i)
#pragma unroll
    for (int j = 0; j < 8; ++j) acc[i][j] = (f32x4){0.f, 0.f, 0.f, 0.f};

  const u16* Abase = A + m0 * K;

#define STAGE(buf, kt) do {                                              \
    const int arow_ = wid * 8;                                           \
    GLDS(Abase + (long)(arow_ + lr) * K + (kt) + scol,                   \
         &(buf)[32768 + arow_ * 64]);                                    \
    _Pragma("unroll")                                                    \
    for (int c_ = 0; c_ < 8; ++c_) {                                     \
      const int row_ = wid * 64 + c_ * 8;                                \
      GLDS(W + (long)(row_ + lr) * K + (kt) + scol, &(buf)[row_ * 64]);  \
    }                                                                    \
  } while (0)

  const int nt = K >> 6;
  STAGE(LDSBUF[0], 0);
  asm volatile("s_waitcnt vmcnt(0)" ::: "memory");
  __builtin_amdgcn_sched_barrier(0);
  __builtin_amdgcn_s_barrier();

  for (int t = 0; t < nt; ++t) {
    u16* const bufc = &LDSBUF[t & 1][0];
    if (t + 1 < nt) STAGE(LDSBUF[(t + 1) & 1], (t + 1) << 6);
#pragma unroll
    for (int ks = 0; ks < 2; ++ks) {
      bf16x8 a0 = ldfrag(bufc + 32768, wm * 32 + r, ks, kg);
      bf16x8 a1 = ldfrag(bufc + 32768, wm * 32 + 16 + r, ks, kg);
      __builtin_amdgcn_s_setprio(1);
#pragma unroll
      for (int ni = 0; ni < 8; ++ni) {
        bf16x8 b = ldfrag(bufc, wn * 128 + ni * 16 + r, ks, kg);
        acc[0][ni] = __builtin_amdgcn_mfma_f32_16x16x32_bf16(a0, b, acc[0][ni], 0, 0, 0);
        acc[1][ni] = __builtin_amdgcn_mfma_f32_16x16x32_bf16(a1, b, acc[1][ni], 0, 0, 0);
      }
      __builtin_amdgcn_s_setprio(0);
    }
    asm volatile("s_waitcnt vmcnt(0)" ::: "memory");
    __builtin_amdgcn_sched_barrier(0);
    __builtin_amdgcn_s_barrier();
  }
#undef STAGE

  const int b0 = (int)(m0 / LQ);
  const int bsplit1 = (b0 + 1) * LQ;
  const int bsplit2 = (b0 + 2) * LQ;

#pragma unroll
  for (int i = 0; i < 8; ++i) {
    const int t = i * 512 + tid;
    const int row = t >> 6, ch = t & 63;
    *(bf16x8*)&EP[row * 516 + ch * 8] =
        *(const bf16x8*)&XB[(m0 + row) * 512 + ch * 8];
  }
  for (int t = tid; t < 1536; t += 512) {
    const int bb = t >> 9, c = t & 511;
    int bi = b0 + bb;
    if (bi > NBATCH - 1) bi = NBATCH - 1;
    LCAV[bb * 512 + c] = cavb[(long)bi * 512 + c];
  }
  __syncthreads();

  float bcol[8];
#pragma unroll
  for (int ni = 0; ni < 8; ++ni) bcol[ni] = bias[wn * 128 + ni * 16 + r];
#pragma unroll
  for (int mi = 0; mi < 2; ++mi)
#pragma unroll
    for (int ni = 0; ni < 8; ++ni) {
      const int col = wn * 128 + ni * 16 + r;
#pragma unroll
      for (int j = 0; j < 4; ++j) {
        const int row = wm * 32 + mi * 16 + kg * 4 + j;
        acc[mi][ni][j] += bcol[ni] + b2f(EP[row * 516 + col]);
      }
    }

#pragma unroll
  for (int mi = 0; mi < 2; ++mi)
#pragma unroll
    for (int j = 0; j < 4; ++j) {
      float s1 = 0.f, s2 = 0.f;
#pragma unroll
      for (int ni = 0; ni < 8; ++ni) {
        const float v = acc[mi][ni][j];
        s1 += v; s2 += v * v;
      }
#pragma unroll
      for (int o = 1; o < 16; o <<= 1) {
        s1 += __shfl_xor(s1, o);
        s2 += __shfl_xor(s2, o);
      }
      if (r == 0) {
        const int row = wm * 32 + mi * 16 + kg * 4 + j;
        LSTAT[row][wn] = s1;
        LSTAT[row][4 + wn] = s2;
      }
    }
  __syncthreads();

  float sc[8], bc[8];
#pragma unroll
  for (int ni = 0; ni < 8; ++ni) {
    const int col = wn * 128 + ni * 16 + r;
    sc[ni] = s1w[col]; bc[ni] = b1w[col];
  }
#pragma unroll
  for (int mi = 0; mi < 2; ++mi)
#pragma unroll
    for (int j = 0; j < 4; ++j) {
      const int row = wm * 32 + mi * 16 + kg * 4 + j;
      const float S1 = LSTAT[row][0] + LSTAT[row][1] + LSTAT[row][2] + LSTAT[row][3];
      const float S2 = LSTAT[row][4] + LSTAT[row][5] + LSTAT[row][6] + LSTAT[row][7];
      const float mean = S1 * (1.f / 512.f);
      const float var = S2 * (1.f / 512.f) - mean * mean;
      const float rstd = rsqrtf(var + 1e-5f);
#pragma unroll
      for (int ni = 0; ni < 8; ++ni)
        acc[mi][ni][j] = (acc[mi][ni][j] - mean) * rstd * sc[ni] + bc[ni];
    }

  // + cav (3-batch select), then LN2
#pragma unroll
  for (int mi = 0; mi < 2; ++mi)
#pragma unroll
    for (int j = 0; j < 4; ++j) {
      const int row = wm * 32 + mi * 16 + kg * 4 + j;
      const int gr = (int)m0 + row;
      const int sel = (gr >= bsplit2) ? 2 : ((gr >= bsplit1) ? 1 : 0);
#pragma unroll
      for (int ni = 0; ni < 8; ++ni) {
        const int col = wn * 128 + ni * 16 + r;
        acc[mi][ni][j] += b2f(LCAV[sel * 512 + col]);
      }
    }
  __syncthreads();
#pragma unroll
  for (int mi = 0; mi < 2; ++mi)
#pragma unroll
    for (int j = 0; j < 4; ++j) {
      float s1 = 0.f, s2 = 0.f;
#pragma unroll
      for (int ni = 0; ni < 8; ++ni) {
        const float v = acc[mi][ni][j];
        s1 += v; s2 += v * v;
      }
#pragma unroll
      for (int o = 1; o < 16; o <<= 1) {
        s1 += __shfl_xor(s1, o);
        s2 += __shfl_xor(s2, o);
      }
      if (r == 0) {
        const int row = wm * 32 + mi * 16 + kg * 4 + j;
        LSTAT[row][wn] = s1;
        LSTAT[row][4 + wn] = s2;
      }
    }
  __syncthreads();
#pragma unroll
  for (int ni = 0; ni < 8; ++ni) {
    const int col = wn * 128 + ni * 16 + r;
    sc[ni] = s2w[col]; bc[ni] = b2w[col];
  }
#pragma unroll
  for (int mi = 0; mi < 2; ++mi)
#pragma unroll
    for (int j = 0; j < 4; ++j) {
      const int row = wm * 32 + mi * 16 + kg * 4 + j;
      const float S1 = LSTAT[row][0] + LSTAT[row][1] + LSTAT[row][2] + LSTAT[row][3];
      const float S2 = LSTAT[row][4] + LSTAT[row][5] + LSTAT[row][6] + LSTAT[row][7];
      const float mean = S1 * (1.f / 512.f);
      const float var = S2 * (1.f / 512.f) - mean * mean;
      const float rstd = rsqrtf(var + 1e-5f);
#pragma unroll
      for (int ni = 0; ni < 8; ++ni)
        acc[mi][ni][j] = (acc[mi][ni][j] - mean) * rstd * sc[ni] + bc[ni];
    }

#pragma unroll
  for (int mi = 0; mi < 2; ++mi)
#pragma unroll
    for (int ni = 0; ni < 8; ++ni) {
      const int col = wn * 128 + ni * 16 + r;
#pragma unroll
      for (int j = 0; j < 4; ++j) {
        const int row = wm * 32 + mi * 16 + kg * 4 + j;
        EP[row * 516 + col] = f2b(acc[mi][ni][j]);
      }
    }
  __syncthreads();
#pragma unroll
  for (int i = 0; i < 8; ++i) {
    const int t = i * 512 + tid;
    const int row = t >> 6, ch = t & 63;
    *(bf16x8*)&XB[(m0 + row) * 512 + ch * 8] =
        *(const bf16x8*)&EP[row * 516 + ch * 8];
  }
}

// ---------------------------------------------------------------------------
// Fused self-attention: one block per (batch, head).
// ---------------------------------------------------------------------------
__global__ __launch_bounds__(256) void attn_k(const u16* __restrict__ qkv,
                                              const int* __restrict__ tgt,
                                              u16* __restrict__ outp)
{
  __shared__ u16 Qs[64 * 72];
  __shared__ u16 Ks[64 * 72];
  __shared__ u16 Vt[64 * 72];
  __shared__ float S[64 * 65];
  __shared__ int stok[64];

  const int bid = blockIdx.x;
  const int b = bid >> 3, h = bid & 7;
  const int tid = threadIdx.x;
  const int tr = tid >> 2, seg = tid & 3;

  if (tid < 64) stok[tid] = (tid < 61) ? tgt[b * 62 + tid] : -1;

  const long rowbase = ((long)(b * LQ + tr)) * 1536 + h * 64;
  if (tr < LQ) {
    const i4v* qsrc = (const i4v*)(qkv + rowbase + seg * 16);
    i4v q0 = qsrc[0], q1 = qsrc[1];
    *(i4v*)&Qs[tr * 72 + seg * 16] = q0;
    *(i4v*)&Qs[tr * 72 + seg * 16 + 8] = q1;
    const i4v* ksrc = (const i4v*)(qkv + rowbase + 512 + seg * 16);
    i4v k0 = ksrc[0], k1 = ksrc[1];
    *(i4v*)&Ks[tr * 72 + seg * 16] = k0;
    *(i4v*)&Ks[tr * 72 + seg * 16 + 8] = k1;
    const u16* vsrc = qkv + rowbase + 1024 + seg * 16;
#pragma unroll
    for (int i = 0; i < 16; ++i) Vt[(seg * 16 + i) * 72 + tr] = vsrc[i];
  } else {
    i4v zz = {0, 0, 0, 0};
    *(i4v*)&Qs[tr * 72 + seg * 16] = zz;
    *(i4v*)&Qs[tr * 72 + seg * 16 + 8] = zz;
    *(i4v*)&Ks[tr * 72 + seg * 16] = zz;
    *(i4v*)&Ks[tr * 72 + seg * 16 + 8] = zz;
#pragma unroll
    for (int i = 0; i < 16; ++i) Vt[(seg * 16 + i) * 72 + tr] = 0;
  }
  __syncthreads();

  const int lane = tid & 63, w = tid >> 6;
  const int r = lane & 15, kg = lane >> 4;

  {   // QK^T
    f32x4 s[4];
#pragma unroll
    for (int ni = 0; ni < 4; ++ni) s[ni] = (f32x4){0.f, 0.f, 0.f, 0.f};
    bf16x8 a0 = *(const bf16x8*)&Qs[(w * 16 + r) * 72 + kg * 8];
    bf16x8 a1 = *(const bf16x8*)&Qs[(w * 16 + r) * 72 + 32 + kg * 8];
#pragma unroll
    for (int ni = 0; ni < 4; ++ni) {
      bf16x8 b0 = *(const bf16x8*)&Ks[(ni * 16 + r) * 72 + kg * 8];
      bf16x8 b1 = *(const bf16x8*)&Ks[(ni * 16 + r) * 72 + 32 + kg * 8];
      s[ni] = __builtin_amdgcn_mfma_f32_16x16x32_bf16(a0, b0, s[ni], 0, 0, 0);
      s[ni] = __builtin_amdgcn_mfma_f32_16x16x32_bf16(a1, b1, s[ni], 0, 0, 0);
    }
#pragma unroll
    for (int ni = 0; ni < 4; ++ni)
#pragma unroll
      for (int j = 0; j < 4; ++j)
        S[(w * 16 + kg * 4 + j) * 65 + ni * 16 + r] = s[ni][j];
  }
  __syncthreads();

  {   // masked softmax
    const int row = tid >> 2, g = tid & 3;
    float vals[16];
    float mx = -3e38f;
#pragma unroll
    for (int i = 0; i < 16; ++i) {
      const int k = g * 16 + i;
      float v = S[row * 65 + k] * 0.125f;
      const bool ok = (k <= row) && (k < LQ) && (stok[k] != PAD_TOK);
      v = ok ? v : -1e30f;
      vals[i] = v;
      mx = fmaxf(mx, v);
    }
    mx = fmaxf(mx, __shfl_xor(mx, 1));
    mx = fmaxf(mx, __shfl_xor(mx, 2));
    float sum = 0.f;
#pragma unroll
    for (int i = 0; i < 16; ++i) { float e = __expf(vals[i] - mx); vals[i] = e; sum += e; }
    sum += __shfl_xor(sum, 1);
    sum += __shfl_xor(sum, 2);
    const float inv = 1.f / sum;
#pragma unroll
    for (int i = 0; i < 16; ++i) Qs[row * 72 + g * 16 + i] = f2b(vals[i] * inv);
  }
  __syncthreads();

  {   // PV, swizzled bounce into Ks
    f32x4 o[4];
#pragma unroll
    for (int ni = 0; ni < 4; ++ni) o[ni] = (f32x4){0.f, 0.f, 0.f, 0.f};
    bf16x8 a0 = *(const bf16x8*)&Qs[(w * 16 + r) * 72 + kg * 8];
    bf16x8 a1 = *(const bf16x8*)&Qs[(w * 16 + r) * 72 + 32 + kg * 8];
#pragma unroll
    for (int ni = 0; ni < 4; ++ni) {
      bf16x8 b0 = *(const bf16x8*)&Vt[(ni * 16 + r) * 72 + kg * 8];
      bf16x8 b1 = *(const bf16x8*)&Vt[(ni * 16 + r) * 72 + 32 + kg * 8];
      o[ni] = __builtin_amdgcn_mfma_f32_16x16x32_bf16(a0, b0, o[ni], 0, 0, 0);
      o[ni] = __builtin_amdgcn_mfma_f32_16x16x32_bf16(a1, b1, o[ni], 0, 0, 0);
    }
#pragma unroll
    for (int ni = 0; ni < 4; ++ni)
#pragma unroll
      for (int j = 0; j < 4; ++j) {
        const int qrow = w * 16 + kg * 4 + j;
        const int col = ni * 16 + r;
        Ks[qrow * 64 + (col ^ ((qrow & 7) << 3))] = f2b(o[ni][j]);
      }
  }
  __syncthreads();

  {   // coalesced O store
    const int row = tid >> 2, sub = tid & 3;
    if (row < LQ) {
      const long obase = ((long)(b * LQ + row)) * 512 + h * 64;
#pragma unroll
      for (int i = 0; i < 2; ++i) {
        const int ch = i * 4 + sub;
        const int phys = ch ^ (row & 7);
        bf16x8 vv = *(const bf16x8*)&Ks[row * 64 + phys * 8];
        *(bf16x8*)&outp[obase + ch * 8] = vv;
      }
    }
  }
}

__device__ __forceinline__ void ln_row(f4& v0, f4& v1,
                                       const float* __restrict__ sw,
                                       const float* __restrict__ bw, int d0) {
  float s1 = v0[0] + v0[1] + v0[2] + v0[3] + v1[0] + v1[1] + v1[2] + v1[3];
  float s2 = v0[0]*v0[0] + v0[1]*v0[1] + v0[2]*v0[2] + v0[3]*v0[3]
           + v1[0]*v1[0] + v1[1]*v1[1] + v1[2]*v1[2] + v1[3]*v1[3];
#pragma unroll
  for (int off = 1; off < 64; off <<= 1) {
    s1 += __shfl_xor(s1, off);
    s2 += __shfl_xor(s2, off);
  }
  const float mean = s1 * (1.f / 512.f);
  const float var = s2 * (1.f / 512.f) - mean * mean;
  const float rstd = rsqrtf(var + 1e-5f);
  const f4* sp = (const f4*)(sw + d0);
  const f4* bp = (const f4*)(bw + d0);
  f4 ss0 = sp[0], ss1 = sp[1], bb0 = bp[0], bb1 = bp[1];
#pragma unroll
  for (int i = 0; i < 4; ++i) {
    v0[i] = (v0[i] - mean) * rstd * ss0[i] + bb0[i];
    v1[i] = (v1[i] - mean) * rstd * ss1[i] + bb1[i];
  }
}

// lnf3: XB = LN(p + XB)
__global__ __launch_bounds__(256) void lnf3_k(const u16* __restrict__ p,
                                              const u16* __restrict__ xr,
                                              const float* __restrict__ s1,
                                              const float* __restrict__ b1,
                                              u16* __restrict__ out)
{
  const int m = blockIdx.x * 4 + (threadIdx.x >> 6);
  const int lane = threadIdx.x & 63;
  const int d0 = lane * 8;
  bf16x8 pv = *(const bf16x8*)(p + (long)m * 512 + d0);
  bf16x8 xv = *(const bf16x8*)(xr + (long)m * 512 + d0);
  f4 v0, v1;
#pragma unroll
  for (int i = 0; i < 4; ++i) {
    v0[i] = b2f((u16)pv[i]) + b2f((u16)xv[i]);
    v1[i] = b2f((u16)pv[4 + i]) + b2f((u16)xv[4 + i]);
  }
  ln_row(v0, v1, s1, b1, d0);
  u16x4* ob = (u16x4*)(out + (long)m * 512 + d0);
  ob[0] = (u16x4){f2b(v0[0]), f2b(v0[1]), f2b(v0[2]), f2b(v0[3])};
  ob[1] = (u16x4){f2b(v1[0]), f2b(v1[1]), f2b(v1[2]), f2b(v1[3])};
}

// Embedding: xb[m] = bf16(emb[tok] + point_out[b] + pos_embed[t])
__global__ __launch_bounds__(256) void embed_k(const float* __restrict__ emb,
                                               const float* __restrict__ pout,
                                               const float* __restrict__ pos,
                                               const int* __restrict__ tgt,
                                               u16* __restrict__ XB)
{
  const int m = blockIdx.x * 4 + (threadIdx.x >> 6);
  const int lane = threadIdx.x & 63;
  const int b = m / LQ, t = m % LQ;
  const int tok = tgt[b * 62 + t];
  const int d0 = lane * 8;
  const f4* e = (const f4*)(emb + (long)tok * 512 + d0);
  const f4* p = (const f4*)(pout + (long)b * 512 + d0);
  const f4* q = (const f4*)(pos + (long)t * 512 + d0);
  f4 v0 = e[0] + p[0] + q[0];
  f4 v1 = e[1] + p[1] + q[1];
  u16x4* xb = (u16x4*)(XB + (long)m * 512 + d0);
  xb[0] = (u16x4){f2b(v0[0]), f2b(v0[1]), f2b(v0[2]), f2b(v0[3])};
  xb[1] = (u16x4){f2b(v1[0]), f2b(v1[1]), f2b(v1[2]), f2b(v1[3])};
}

// merged f32->bf16 conversion of the 5 plain weight blocks
__global__ void cvtall_k(const float* __restrict__ s0, const float* __restrict__ s1,
                         const float* __restrict__ s2, const float* __restrict__ s3,
                         const float* __restrict__ s4,
                         u16* __restrict__ d0, u16* __restrict__ d1,
                         u16* __restrict__ d2, u16* __restrict__ d3,
                         u16* __restrict__ d4)
{
  const int N0 = 1179648;
  const int N1 = N0 + 393216;
  const int N2 = N1 + 393216;
  const int N3 = N2 + 1572864;
  const int N4 = N3 + 1572864;
  for (int i = blockIdx.x * 256 + threadIdx.x; i < N4; i += gridDim.x * 256) {
    const float* s; u16* d; int k;
    if (i < N0)      { s = s0; d = d0; k = i; }
    else if (i < N1) { s = s1; d = d1; k = i - N0; }
    else if (i < N2) { s = s2; d = d2; k = i - N1; }
    else if (i < N3) { s = s3; d = d3; k = i - N2; }
    else             { s = s4; d = d4; k = i - N3; }
    f4 v = ((const f4*)s)[k];
    ((u16x4*)d)[k] = (u16x4){f2b(v[0]), f2b(v[1]), f2b(v[2]), f2b(v[3])};
  }
}

__global__ void cvt_ca_v_k(const float* __restrict__ ca_inw, u16* __restrict__ dst) {
  const int i = blockIdx.x * 256 + threadIdx.x;
  if (i >= 393216) return;
  const int l = i >> 16, rem = i & 65535;
  f4 v = ((const f4*)ca_inw)[l * 196608 + 131072 + rem];
  ((u16x4*)dst)[i] = (u16x4){f2b(v[0]), f2b(v[1]), f2b(v[2]), f2b(v[3])};
}

// out_w padded to [1280][512] bf16, rows >=1027 zero
__global__ void cvt_outw_k(const float* __restrict__ out_w, u16* __restrict__ dst) {
  const int i = blockIdx.x * 256 + threadIdx.x;
  if (i >= 163840) return;
  const int row = (i * 4) >> 9;
  u16x4 o = {0, 0, 0, 0};
  if (row < 1027) {
    f4 v = ((const f4*)out_w)[i];
    o = (u16x4){f2b(v[0]), f2b(v[1]), f2b(v[2]), f2b(v[3])};
  }
  ((u16x4*)dst)[i] = o;
}

__global__ void cvt_outb_k(const float* __restrict__ out_b, float* __restrict__ dst) {
  const int i = blockIdx.x * 256 + threadIdx.x;
  if (i >= 1280) return;
  dst[i] = (i < 1027) ? out_b[i] : 0.f;
}

__global__ void cvt_memb_k(const float* __restrict__ enc, u16* __restrict__ dst) {
  const int i = blockIdx.x * 256 + threadIdx.x;
  if (i >= 32768) return;
  const int b = (i * 4) >> 9, d = (i * 4) & 511;
  f4 v = ((const f4*)enc)[(b * 8192 + d) >> 2];
  ((u16x4*)dst)[i] = (u16x4){f2b(v[0]), f2b(v[1]), f2b(v[2]), f2b(v[3])};
}

// ---------------------------------------------------------------------------
// Workspace layout (bytes)
// ---------------------------------------------------------------------------
static constexpr size_t XB_OFF    = 0;            // bf16 [15616][512]
static constexpr size_t P_OFF     = 15990784;     // bf16 [15616][512]
static constexpr size_t BIG_OFF   = 31981568;     // bf16 qkv/h1
static constexpr size_t ATT_OFF   = 95944704;     // bf16 [15616][512]
static constexpr size_t WSA_OFF   = 111935488;    // bf16 [6][1536][512]
static constexpr size_t WSO_OFF   = 121372672;    // bf16 [6][512][512]
static constexpr size_t WCAV_OFF  = 124518400;    // bf16 [6][512][512]
static constexpr size_t WCO_OFF   = 127664128;    // bf16 [6][512][512]
static constexpr size_t WF1_OFF   = 130809856;    // bf16 [6][2048][512]
static constexpr size_t WF2_OFF   = 143392768;    // bf16 [6][512][2048]
static constexpr size_t WOUT_OFF  = 155975680;    // bf16 [1280][512]
static constexpr size_t BOUT_OFF  = 157286400;    // f32  [1280]
static constexpr size_t MEMB_OFF  = 157291520;    // bf16 [256][512]
static constexpr size_t CATMP_OFF = 157553664;    // bf16 [6][256][512]
static constexpr size_t CAVB_OFF  = 159126528;    // bf16 [6][256][512]

extern "C" void kernel_launch(void* const* d_in, const int* in_sizes, int n_in,
                              void* d_out, int out_size, void* d_ws, size_t ws_size,
                              hipStream_t stream) {
  (void)in_sizes; (void)n_in; (void)out_size; (void)ws_size;
  const float* encoder_out = (const float*)d_in[0];
  const float* point_out   = (const float*)d_in[1];
  const float* emb         = (const float*)d_in[2];
  const float* pos         = (const float*)d_in[3];
  const float* sa_inw      = (const float*)d_in[4];
  const float* sa_inb      = (const float*)d_in[5];
  const float* sa_outw     = (const float*)d_in[6];
  const float* sa_outb     = (const float*)d_in[7];
  const float* ca_inw      = (const float*)d_in[8];
  const float* ca_inb      = (const float*)d_in[9];
  const float* ca_outw     = (const float*)d_in[10];
  const float* ca_outb     = (const float*)d_in[11];
  const float* ln1_s       = (const float*)d_in[12];
  const float* ln1_b       = (const float*)d_in[13];
  const float* ln2_s       = (const float*)d_in[14];
  const float* ln2_b       = (const float*)d_in[15];
  const float* ln3_s       = (const float*)d_in[16];
  const float* ln3_b       = (const float*)d_in[17];
  const float* ff1_w       = (const float*)d_in[18];
  const float* ff1_b       = (const float*)d_in[19];
  const float* ff2_w       = (const float*)d_in[20];
  const float* ff2_b       = (const float*)d_in[21];
  const float* out_w       = (const float*)d_in[22];
  const float* out_b       = (const float*)d_in[23];
  const int*   tgt         = (const int*)d_in[24];

  char* ws = (char*)d_ws;
  u16*   XB    = (u16*)(ws + XB_OFF);
  u16*   P     = (u16*)(ws + P_OFF);
  u16*   BIG   = (u16*)(ws + BIG_OFF);
  u16*   ATT   = (u16*)(ws + ATT_OFF);
  u16*   WSA   = (u16*)(ws + WSA_OFF);
  u16*   WSO   = (u16*)(ws + WSO_OFF);
  u16*   WCAV  = (u16*)(ws + WCAV_OFF);
  u16*   WCO   = (u16*)(ws + WCO_OFF);
  u16*   WF1   = (u16*)(ws + WF1_OFF);
  u16*   WF2   = (u16*)(ws + WF2_OFF);
  u16*   WOUT  = (u16*)(ws + WOUT_OFF);
  float* BOUT  = (float*)(ws + BOUT_OFF);
  u16*   MEMB  = (u16*)(ws + MEMB_OFF);
  u16*   CATMP = (u16*)(ws + CATMP_OFF);
  u16*   CAVB  = (u16*)(ws + CAVB_OFF);

  // ---- weight conversion ----
  cvtall_k<<<dim3(2048), dim3(256), 0, stream>>>(
      sa_inw, sa_outw, ca_outw, ff1_w, ff2_w, WSA, WSO, WCO, WF1, WF2);
  cvt_ca_v_k<<<dim3(1536), dim3(256), 0, stream>>>(ca_inw, WCAV);
  cvt_outw_k<<<dim3(640), dim3(256), 0, stream>>>(out_w, WOUT);
  cvt_outb_k<<<dim3(5), dim3(256), 0, stream>>>(out_b, BOUT);
  cvt_memb_k<<<dim3(128), dim3(256), 0, stream>>>(encoder_out, MEMB);

  // ---- embedding ----
  embed_k<<<dim3(MTOT / 4), dim3(256), 0, stream>>>(emb, point_out, pos, tgt, XB);

  // ---- cross-attention vectors (x-independent), bf16 ----
  gemm_bt<64><<<dim3(4, 4, 6), dim3(256), 0, stream>>>(
      MEMB, WCAV, ca_inb + 1024, nullptr, CATMP,
      256, 512, 512, 512, 512, 0,
      0L, 262144L, 1536L, 131072L);
  gemm_bt<64><<<dim3(4, 4, 6), dim3(256), 0, stream>>>(
      CATMP, WCO, ca_outb, nullptr, CAVB,
      256, 512, 512, 512, 512, 0,
      131072L, 262144L, 512L, 131072L);

  for (int l = 0; l < 6; ++l) {
    // QKV: 128x256 tiles, grid 6x122
    gemm_bt2<<<dim3(6, 122), dim3(512), 0, stream>>>(
        XB, WSA + (long)l * 786432, sa_inb + l * 1536, nullptr, BIG,
        1536, 512, 1536, 1536, 0);
    // fused attention
    attn_k<<<dim3(2048), dim3(256), 0, stream>>>(BIG, tgt, ATT);
    // out-proj + resid + LN1 + CA + LN2 -> XB (fused full-row, K=512 only)
    gemmln_k<<<dim3(244), dim3(512), 0, stream>>>(
        ATT, WSO + (long)l * 262144, sa_outb + l * 512,
        CAVB + (long)l * 131072,
        ln1_s + l * 512, ln1_b + l * 512, ln2_s + l * 512, ln2_b + l * 512,
        XB, 512);
    // FF1 + ReLU: 128x256 tiles, grid 8x122
    gemm_bt2<<<dim3(8, 122), dim3(512), 0, stream>>>(
        XB, WF1 + (long)l * 1048576, ff1_b + l * 2048, nullptr, BIG,
        2048, 512, 2048, 2048, 1);
    // FF2 -> P (split: many blocks for latency hiding)
    gemm_bt<64><<<dim3(4, 244, 1), dim3(256), 0, stream>>>(
        BIG, WF2 + (long)l * 1048576, ff2_b + l * 512, nullptr, P,
        MTOT, 512, 2048, 512, 512, 0, 0L, 0L, 0L, 0L);
    // resid + LN3 -> XB
    lnf3_k<<<dim3(MTOT / 4), dim3(256), 0, stream>>>(
        P, XB, ln3_s + l * 512, ln3_b + l * 512, XB);
  }

  // ---- final logits: 128x256 tiles, N padded 1280, f32 out ----
  gemm_bt2<<<dim3(5, 122), dim3(512), 0, stream>>>(
      XB, WOUT, BOUT, (float*)d_out, nullptr,
      1280, 512, 1027, 1027, 0);
}

// Round 9
// 1106.855 us; speedup vs baseline: 1.1770x; 1.0153x over previous
//
#include <hip/hip_runtime.h>
#include <stdint.h>
#include <stddef.h>

typedef unsigned short u16;
typedef float f4 __attribute__((ext_vector_type(4)));
typedef float f32x4 __attribute__((ext_vector_type(4)));
typedef short bf16x8 __attribute__((ext_vector_type(8)));
typedef u16 u16x4 __attribute__((ext_vector_type(4)));
typedef int i4v __attribute__((ext_vector_type(4)));

#define PAD_TOK 1026
#define LQ 61
#define NBATCH 256
#define MTOT (NBATCH * LQ)   // 15616 = 244*64 = 122*128

__device__ __forceinline__ u16 f2b(float f) {
  uint32_t x = __float_as_uint(f);
  x += 0x7fff + ((x >> 16) & 1);   // RNE
  return (u16)(x >> 16);
}
__device__ __forceinline__ float b2f(u16 u) {
  return __uint_as_float(((uint32_t)u) << 16);
}
__device__ __forceinline__ u16x4 cvt4(f4 v) {
  return (u16x4){f2b(v[0]), f2b(v[1]), f2b(v[2]), f2b(v[3])};
}

#define GLDS(gptr, lptr) __builtin_amdgcn_global_load_lds( \
    (const __attribute__((address_space(1))) void*)(gptr), \
    (__attribute__((address_space(3))) void*)(lptr), 16, 0, 0)

__device__ __forceinline__ bf16x8 ldfrag(const u16* buf, int row, int ksl, int kg) {
  const int chunk = (ksl * 4 + kg) ^ (row & 7);
  return *(const bf16x8*)&buf[row * 64 + chunk * 8];
}

// ---------------------------------------------------------------------------
// 128x256 bf16 B^T GEMM, BK=64, 512 threads (8 waves, 2M x 4N, wave 64x64).
// bf16 out: two-half LDS bounce. f32 out: quarter-pass LDS bounce with
// row-contiguous 64B/thread stores (fixes odd-ldc write scatter).
// ---------------------------------------------------------------------------
__global__ __launch_bounds__(512) void gemm_bt2(
    const u16* __restrict__ A, const u16* __restrict__ W,
    const float* __restrict__ bias,
    float* __restrict__ Cf, u16* __restrict__ Cb,
    int N, int K, int Nreal, int ldc, int relu)
{
  __shared__ u16 SH[384 * 64];         // As 128x64 | Bs 256x64 ; bounce buffer
  u16* const As = SH;
  u16* const Bs = SH + 8192;

  // bijective XCD swizzle (m204)
  const int gx = gridDim.x;
  const int nwg = gx * gridDim.y;
  const int orig = blockIdx.y * gx + blockIdx.x;
  const int q8 = nwg >> 3, r8 = nwg & 7;
  const int xcd = orig & 7, off = orig >> 3;
  const int nid = (xcd < r8 ? xcd * (q8 + 1) : r8 * (q8 + 1) + (xcd - r8) * q8) + off;
  const int bx = nid % gx, by = nid / gx;

  const int tid = threadIdx.x;
  const int wid = tid >> 6, lane = tid & 63;
  const int wm = wid >> 2, wn = wid & 3;
  const long m0 = (long)by * 128;
  const long n0 = (long)bx * 256;

  const int lr = lane >> 3;
  const int lc = lane & 7;
  const int scol = ((lc ^ lr) << 3);

  f32x4 acc[4][4];
#pragma unroll
  for (int i = 0; i < 4; ++i)
#pragma unroll
    for (int j = 0; j < 4; ++j) acc[i][j] = (f32x4){0.f, 0.f, 0.f, 0.f};

  const u16* Abase = A + m0 * K;
  const u16* Wbase = W + n0 * K;
  const int r = lane & 15, kg = lane >> 4;

  for (int kt = 0; kt < K; kt += 64) {
#pragma unroll
    for (int c = 0; c < 2; ++c) {
      const int row = wid * 16 + c * 8;
      GLDS(Abase + (long)(row + lr) * K + kt + scol, &As[row * 64]);
    }
#pragma unroll
    for (int c = 0; c < 4; ++c) {
      const int row = wid * 32 + c * 8;
      GLDS(Wbase + (long)(row + lr) * K + kt + scol, &Bs[row * 64]);
    }
    __syncthreads();

#pragma unroll
    for (int ks = 0; ks < 2; ++ks) {
      bf16x8 a[4], b[4];
#pragma unroll
      for (int mi = 0; mi < 4; ++mi)
        a[mi] = ldfrag(As, wm * 64 + mi * 16 + r, ks, kg);
#pragma unroll
      for (int ni = 0; ni < 4; ++ni)
        b[ni] = ldfrag(Bs, wn * 64 + ni * 16 + r, ks, kg);
#pragma unroll
      for (int mi = 0; mi < 4; ++mi)
#pragma unroll
        for (int ni = 0; ni < 4; ++ni)
          acc[mi][ni] = __builtin_amdgcn_mfma_f32_16x16x32_bf16(a[mi], b[ni], acc[mi][ni], 0, 0, 0);
    }
    __syncthreads();
  }

  const int cr4 = (lane >> 4) * 4;
  const int cc = lane & 15;

  if (Cb) {
#pragma unroll
    for (int half = 0; half < 2; ++half) {
      if (wm == half) {
#pragma unroll
        for (int ni = 0; ni < 4; ++ni) {
          const int coll = wn * 64 + ni * 16 + cc;
          const float bv = bias[(int)n0 + coll];
#pragma unroll
          for (int mi = 0; mi < 4; ++mi) {
#pragma unroll
            for (int j = 0; j < 4; ++j) {
              const int rowl = mi * 16 + cr4 + j;
              float v = acc[mi][ni][j] + bv;
              if (relu) v = fmaxf(v, 0.f);
              const int phys = (coll >> 3) ^ (rowl & 31);
              SH[rowl * 256 + phys * 8 + (coll & 7)] = f2b(v);
            }
          }
        }
      }
      __syncthreads();
#pragma unroll
      for (int i = 0; i < 4; ++i) {
        const int t = i * 512 + tid;
        const int row = t >> 5, ch = t & 31;
        const int n = (int)n0 + ch * 8;
        if (n < Nreal) {
          const int phys = ch ^ (row & 31);
          *(bf16x8*)&Cb[(m0 + half * 64 + row) * (long)N + n] =
              *(const bf16x8*)&SH[row * 256 + phys * 8];
        }
      }
      __syncthreads();
    }
  } else {
    // f32 path: quarter-pass bounce (32 rows x 256 f32, stride 260)
    float* SHf = (float*)SH;
#pragma unroll
    for (int q = 0; q < 4; ++q) {
      if (wm == (q >> 1)) {
        const int mib = (q & 1) * 2;
#pragma unroll
        for (int ni = 0; ni < 4; ++ni) {
          const int coll = wn * 64 + ni * 16 + cc;
          const float bv = bias[(int)n0 + coll];
#pragma unroll
          for (int mi2 = 0; mi2 < 2; ++mi2) {
#pragma unroll
            for (int j = 0; j < 4; ++j) {
              const int rowl = mi2 * 16 + cr4 + j;       // 0..31
              float v = acc[mib + mi2][ni][j] + bv;
              if (relu) v = fmaxf(v, 0.f);
              SHf[rowl * 260 + coll] = v;
            }
          }
        }
      }
      __syncthreads();
      {
        const int row = tid >> 4, c = tid & 15;          // 32 rows x 16 chunks
        const int nbase = (int)n0 + c * 16;
        const long gro = (m0 + q * 32 + row) * (long)ldc;
        if (nbase + 16 <= Nreal) {
#pragma unroll
          for (int e = 0; e < 16; ++e)
            Cf[gro + nbase + e] = SHf[row * 260 + c * 16 + e];
        } else if (nbase < Nreal) {
          for (int e = 0; e < Nreal - nbase; ++e)
            Cf[gro + nbase + e] = SHf[row * 260 + c * 16 + e];
        }
      }
      __syncthreads();
    }
  }
}

// ---------------------------------------------------------------------------
// 64x256 bf16 B^T GEMM (FF2 shape), BK=64, 512 threads (8 waves, 2M x 4N,
// wave 32x64). 40KB LDS -> 4 blocks/CU; N-split halved vs BN=128.
// ---------------------------------------------------------------------------
__global__ __launch_bounds__(512) void gemm_bt3(
    const u16* __restrict__ A, const u16* __restrict__ W,
    const float* __restrict__ bias, u16* __restrict__ Cb,
    int N, int K, int relu)
{
  __shared__ u16 SH[320 * 64];         // As 64x64 (8KB) | Bs 256x64 (32KB)
  u16* const As = SH;
  u16* const Bs = SH + 4096;

  const int gx = gridDim.x;
  const int nwg = gx * gridDim.y;
  const int orig = blockIdx.y * gx + blockIdx.x;
  const int q8 = nwg >> 3, r8 = nwg & 7;
  const int xcd = orig & 7, off = orig >> 3;
  const int nid = (xcd < r8 ? xcd * (q8 + 1) : r8 * (q8 + 1) + (xcd - r8) * q8) + off;
  const int bx = nid % gx, by = nid / gx;

  const int tid = threadIdx.x;
  const int wid = tid >> 6, lane = tid & 63;
  const int wm = wid >> 2, wn = wid & 3;
  const long m0 = (long)by * 64;
  const long n0 = (long)bx * 256;

  const int lr = lane >> 3;
  const int lc = lane & 7;
  const int scol = ((lc ^ lr) << 3);

  f32x4 acc[2][4];
#pragma unroll
  for (int i = 0; i < 2; ++i)
#pragma unroll
    for (int j = 0; j < 4; ++j) acc[i][j] = (f32x4){0.f, 0.f, 0.f, 0.f};

  const u16* Abase = A + m0 * K;
  const u16* Wbase = W + n0 * K;
  const int r = lane & 15, kg = lane >> 4;

  for (int kt = 0; kt < K; kt += 64) {
    {
      const int arow = wid * 8;
      GLDS(Abase + (long)(arow + lr) * K + kt + scol, &As[arow * 64]);
#pragma unroll
      for (int c = 0; c < 4; ++c) {
        const int row = wid * 32 + c * 8;
        GLDS(Wbase + (long)(row + lr) * K + kt + scol, &Bs[row * 64]);
      }
    }
    __syncthreads();

#pragma unroll
    for (int ks = 0; ks < 2; ++ks) {
      bf16x8 a0 = ldfrag(As, wm * 32 + r, ks, kg);
      bf16x8 a1 = ldfrag(As, wm * 32 + 16 + r, ks, kg);
#pragma unroll
      for (int ni = 0; ni < 4; ++ni) {
        bf16x8 b = ldfrag(Bs, wn * 64 + ni * 16 + r, ks, kg);
        acc[0][ni] = __builtin_amdgcn_mfma_f32_16x16x32_bf16(a0, b, acc[0][ni], 0, 0, 0);
        acc[1][ni] = __builtin_amdgcn_mfma_f32_16x16x32_bf16(a1, b, acc[1][ni], 0, 0, 0);
      }
    }
    __syncthreads();
  }

  const int cr4 = (lane >> 4) * 4;
  const int cc = lane & 15;

  // bounce 64x256 bf16 (32KB) into SH, then coalesced 512B/row stores
#pragma unroll
  for (int ni = 0; ni < 4; ++ni) {
    const int coll = wn * 64 + ni * 16 + cc;
    const float bv = bias[(int)n0 + coll];
#pragma unroll
    for (int mi = 0; mi < 2; ++mi) {
#pragma unroll
      for (int j = 0; j < 4; ++j) {
        const int rowl = wm * 32 + mi * 16 + cr4 + j;    // 0..63
        float v = acc[mi][ni][j] + bv;
        if (relu) v = fmaxf(v, 0.f);
        const int phys = (coll >> 3) ^ (rowl & 31);
        SH[rowl * 256 + phys * 8 + (coll & 7)] = f2b(v);
      }
    }
  }
  __syncthreads();
#pragma unroll
  for (int i = 0; i < 4; ++i) {
    const int t = i * 512 + tid;
    const int row = t >> 5, ch = t & 31;
    const int n = (int)n0 + ch * 8;
    const int phys = ch ^ (row & 31);
    *(bf16x8*)&Cb[(m0 + row) * (long)N + n] =
        *(const bf16x8*)&SH[row * 256 + phys * 8];
  }
}

// ---------------------------------------------------------------------------
// bf16 B^T GEMM, BM x 128 tile, BK=64, 4 waves (CA batch GEMMs).
// ---------------------------------------------------------------------------
template<int BM>
__global__ __launch_bounds__(256) void gemm_bt(
    const u16* __restrict__ A, const u16* __restrict__ W,
    const float* __restrict__ bias,
    float* __restrict__ Cf, u16* __restrict__ Cb,
    int M, int N, int K, int Nreal, int ldc, int relu,
    long aZ, long wZ, long bZ, long cZ)
{
  constexpr int MI = BM / 32;
  const int z = blockIdx.z;
  A += z * aZ; W += z * wZ; bias += z * bZ;
  if (Cf) Cf += z * cZ;
  if (Cb) Cb += z * cZ;

  __shared__ u16 As[BM * 64];
  __shared__ u16 Bs[128 * 64];

  const int gx = gridDim.x;
  const int nwg = gx * gridDim.y;
  const int orig = blockIdx.y * gx + blockIdx.x;
  const int q8 = nwg >> 3, r8 = nwg & 7;
  const int xcd = orig & 7, off = orig >> 3;
  const int nid = (xcd < r8 ? xcd * (q8 + 1) : r8 * (q8 + 1) + (xcd - r8) * q8) + off;
  const int bx = nid % gx, by = nid / gx;

  const int tid = threadIdx.x;
  const int wid = tid >> 6, lane = tid & 63;
  const int wr = wid >> 1, wc = wid & 1;
  const long m0 = (long)by * BM;
  const long n0 = (long)bx * 128;

  const int lr = lane >> 3;
  const int lc = lane & 7;
  const int scol = ((lc ^ lr) << 3);

  f32x4 acc[MI][4];
#pragma unroll
  for (int i = 0; i < MI; ++i)
#pragma unroll
    for (int j = 0; j < 4; ++j) acc[i][j] = (f32x4){0.f, 0.f, 0.f, 0.f};

  const u16* Abase = A + m0 * K;
  const u16* Wbase = W + n0 * K;
  const int r = lane & 15, kg = lane >> 4;

  for (int kt = 0; kt < K; kt += 64) {
#pragma unroll
    for (int c = 0; c < BM / 32; ++c) {
      const int row = wid * (BM / 4) + c * 8;
      GLDS(Abase + (long)(row + lr) * K + kt + scol, &As[row * 64]);
    }
#pragma unroll
    for (int c = 0; c < 4; ++c) {
      const int row = wid * 32 + c * 8;
      GLDS(Wbase + (long)(row + lr) * K + kt + scol, &Bs[row * 64]);
    }
    __syncthreads();

#pragma unroll
    for (int ks = 0; ks < 2; ++ks) {
      bf16x8 a[MI], b[4];
#pragma unroll
      for (int mi = 0; mi < MI; ++mi)
        a[mi] = ldfrag(As, wr * (BM / 2) + mi * 16 + r, ks, kg);
#pragma unroll
      for (int ni = 0; ni < 4; ++ni)
        b[ni] = ldfrag(Bs, wc * 64 + ni * 16 + r, ks, kg);
#pragma unroll
      for (int mi = 0; mi < MI; ++mi)
#pragma unroll
        for (int ni = 0; ni < 4; ++ni)
          acc[mi][ni] = __builtin_amdgcn_mfma_f32_16x16x32_bf16(a[mi], b[ni], acc[mi][ni], 0, 0, 0);
    }
    __syncthreads();
  }

  const int cr4 = (lane >> 4) * 4;
  const int cc = lane & 15;

  if (Cb) {
#pragma unroll
    for (int ni = 0; ni < 4; ++ni) {
      const int coll = wc * 64 + ni * 16 + cc;
      const float bv = bias[(int)n0 + coll];
#pragma unroll
      for (int mi = 0; mi < MI; ++mi) {
#pragma unroll
        for (int j = 0; j < 4; ++j) {
          const int rowl = wr * (BM / 2) + mi * 16 + cr4 + j;
          float v = acc[mi][ni][j] + bv;
          if (relu) v = fmaxf(v, 0.f);
          const int sw = (rowl & 7) << 3;
          u16* half = (coll & 64) ? Bs : As;
          half[rowl * 64 + ((coll & 63) ^ sw)] = f2b(v);
        }
      }
    }
    __syncthreads();
    constexpr int PT = BM / 16;
#pragma unroll
    for (int i = 0; i < PT; ++i) {
      const int t = i * 256 + tid;
      const int row = t >> 4, ch = t & 15;
      const int n = (int)n0 + ch * 8;
      if (n < Nreal) {
        const int phys = (ch & 7) ^ (row & 7);
        const u16* half = (ch < 8) ? As : Bs;
        bf16x8 vv = *(const bf16x8*)&half[row * 64 + phys * 8];
        *(bf16x8*)&Cb[(m0 + row) * (long)N + n] = vv;
      }
    }
  } else {
#pragma unroll
    for (int ni = 0; ni < 4; ++ni) {
      const int n = (int)n0 + wc * 64 + ni * 16 + cc;
      if (n >= Nreal) continue;
      const float bv = bias[n];
#pragma unroll
      for (int mi = 0; mi < MI; ++mi) {
#pragma unroll
        for (int j = 0; j < 4; ++j) {
          const long m = m0 + wr * (BM / 2) + mi * 16 + cr4 + j;
          float v = acc[mi][ni][j] + bv;
          if (relu) v = fmaxf(v, 0.f);
          Cf[m * ldc + n] = v;
        }
      }
    }
  }
}

// ---------------------------------------------------------------------------
// Full-row fused GEMM+LN (proj only, K=512): BM=64, BN=512, 8 waves.
// XB = LN2( LN1(A@W^T + bias + XB) + cav ). 64-row tile spans up to THREE
// 61-row batches -> LCAV[3], sel in {0,1,2}. 2-phase dbuf staging.
// ---------------------------------------------------------------------------
__global__ __launch_bounds__(512) void gemmln_k(
    const u16* __restrict__ A, const u16* __restrict__ W,
    const float* __restrict__ bias,
    const u16* __restrict__ cavb,
    const float* __restrict__ s1w, const float* __restrict__ b1w,
    const float* __restrict__ s2w, const float* __restrict__ b2w,
    u16* __restrict__ XB, int K)
{
  __shared__ u16 LDSBUF[2][36864];
  __shared__ float LSTAT[64][8];
  __shared__ u16 LCAV[1536];
  u16* const EP = &LDSBUF[0][0];       // epilogue reuse, row stride 516

  const int nwg = gridDim.x;
  const int orig = blockIdx.x;
  const int q8 = nwg >> 3, r8 = nwg & 7;
  const int xcd = orig & 7, off = orig >> 3;
  const int by = (xcd < r8 ? xcd * (q8 + 1) : r8 * (q8 + 1) + (xcd - r8) * q8) + off;

  const int tid = threadIdx.x;
  const int wid = tid >> 6, lane = tid & 63;
  const int wm = wid >> 2, wn = wid & 3;
  const long m0 = (long)by * 64;

  const int lr = lane >> 3, lc = lane & 7;
  const int scol = ((lc ^ lr) << 3);
  const int r = lane & 15, kg = lane >> 4;

  f32x4 acc[2][8];
#pragma unroll
  for (int i = 0; i < 2; ++i)
#pragma unroll
    for (int j = 0; j < 8; ++j) acc[i][j] = (f32x4){0.f, 0.f, 0.f, 0.f};

  const u16* Abase = A + m0 * K;

#define STAGE(buf, kt) do {                                              \
    const int arow_ = wid * 8;                                           \
    GLDS(Abase + (long)(arow_ + lr) * K + (kt) + scol,                   \
         &(buf)[32768 + arow_ * 64]);                                    \
    _Pragma("unroll")                                                    \
    for (int c_ = 0; c_ < 8; ++c_) {                                     \
      const int row_ = wid * 64 + c_ * 8;                                \
      GLDS(W + (long)(row_ + lr) * K + (kt) + scol, &(buf)[row_ * 64]);  \
    }                                                                    \
  } while (0)

  const int nt = K >> 6;
  STAGE(LDSBUF[0], 0);
  asm volatile("s_waitcnt vmcnt(0)" ::: "memory");
  __builtin_amdgcn_sched_barrier(0);
  __builtin_amdgcn_s_barrier();

  for (int t = 0; t < nt; ++t) {
    u16* const bufc = &LDSBUF[t & 1][0];
    if (t + 1 < nt) STAGE(LDSBUF[(t + 1) & 1], (t + 1) << 6);
#pragma unroll
    for (int ks = 0; ks < 2; ++ks) {
      bf16x8 a0 = ldfrag(bufc + 32768, wm * 32 + r, ks, kg);
      bf16x8 a1 = ldfrag(bufc + 32768, wm * 32 + 16 + r, ks, kg);
      __builtin_amdgcn_s_setprio(1);
#pragma unroll
      for (int ni = 0; ni < 8; ++ni) {
        bf16x8 b = ldfrag(bufc, wn * 128 + ni * 16 + r, ks, kg);
        acc[0][ni] = __builtin_amdgcn_mfma_f32_16x16x32_bf16(a0, b, acc[0][ni], 0, 0, 0);
        acc[1][ni] = __builtin_amdgcn_mfma_f32_16x16x32_bf16(a1, b, acc[1][ni], 0, 0, 0);
      }
      __builtin_amdgcn_s_setprio(0);
    }
    asm volatile("s_waitcnt vmcnt(0)" ::: "memory");
    __builtin_amdgcn_sched_barrier(0);
    __builtin_amdgcn_s_barrier();
  }
#undef STAGE

  const int b0 = (int)(m0 / LQ);
  const int bsplit1 = (b0 + 1) * LQ;
  const int bsplit2 = (b0 + 2) * LQ;

#pragma unroll
  for (int i = 0; i < 8; ++i) {
    const int t = i * 512 + tid;
    const int row = t >> 6, ch = t & 63;
    *(bf16x8*)&EP[row * 516 + ch * 8] =
        *(const bf16x8*)&XB[(m0 + row) * 512 + ch * 8];
  }
  for (int t = tid; t < 1536; t += 512) {
    const int bb = t >> 9, c = t & 511;
    int bi = b0 + bb;
    if (bi > NBATCH - 1) bi = NBATCH - 1;
    LCAV[bb * 512 + c] = cavb[(long)bi * 512 + c];
  }
  __syncthreads();

  float bcol[8];
#pragma unroll
  for (int ni = 0; ni < 8; ++ni) bcol[ni] = bias[wn * 128 + ni * 16 + r];
#pragma unroll
  for (int mi = 0; mi < 2; ++mi)
#pragma unroll
    for (int ni = 0; ni < 8; ++ni) {
      const int col = wn * 128 + ni * 16 + r;
#pragma unroll
      for (int j = 0; j < 4; ++j) {
        const int row = wm * 32 + mi * 16 + kg * 4 + j;
        acc[mi][ni][j] += bcol[ni] + b2f(EP[row * 516 + col]);
      }
    }

#pragma unroll
  for (int mi = 0; mi < 2; ++mi)
#pragma unroll
    for (int j = 0; j < 4; ++j) {
      float s1 = 0.f, s2 = 0.f;
#pragma unroll
      for (int ni = 0; ni < 8; ++ni) {
        const float v = acc[mi][ni][j];
        s1 += v; s2 += v * v;
      }
#pragma unroll
      for (int o = 1; o < 16; o <<= 1) {
        s1 += __shfl_xor(s1, o);
        s2 += __shfl_xor(s2, o);
      }
      if (r == 0) {
        const int row = wm * 32 + mi * 16 + kg * 4 + j;
        LSTAT[row][wn] = s1;
        LSTAT[row][4 + wn] = s2;
      }
    }
  __syncthreads();

  float sc[8], bc[8];
#pragma unroll
  for (int ni = 0; ni < 8; ++ni) {
    const int col = wn * 128 + ni * 16 + r;
    sc[ni] = s1w[col]; bc[ni] = b1w[col];
  }
#pragma unroll
  for (int mi = 0; mi < 2; ++mi)
#pragma unroll
    for (int j = 0; j < 4; ++j) {
      const int row = wm * 32 + mi * 16 + kg * 4 + j;
      const float S1 = LSTAT[row][0] + LSTAT[row][1] + LSTAT[row][2] + LSTAT[row][3];
      const float S2 = LSTAT[row][4] + LSTAT[row][5] + LSTAT[row][6] + LSTAT[row][7];
      const float mean = S1 * (1.f / 512.f);
      const float var = S2 * (1.f / 512.f) - mean * mean;
      const float rstd = rsqrtf(var + 1e-5f);
#pragma unroll
      for (int ni = 0; ni < 8; ++ni)
        acc[mi][ni][j] = (acc[mi][ni][j] - mean) * rstd * sc[ni] + bc[ni];
    }

  // + cav (3-batch select), then LN2
#pragma unroll
  for (int mi = 0; mi < 2; ++mi)
#pragma unroll
    for (int j = 0; j < 4; ++j) {
      const int row = wm * 32 + mi * 16 + kg * 4 + j;
      const int gr = (int)m0 + row;
      const int sel = (gr >= bsplit2) ? 2 : ((gr >= bsplit1) ? 1 : 0);
#pragma unroll
      for (int ni = 0; ni < 8; ++ni) {
        const int col = wn * 128 + ni * 16 + r;
        acc[mi][ni][j] += b2f(LCAV[sel * 512 + col]);
      }
    }
  __syncthreads();
#pragma unroll
  for (int mi = 0; mi < 2; ++mi)
#pragma unroll
    for (int j = 0; j < 4; ++j) {
      float s1 = 0.f, s2 = 0.f;
#pragma unroll
      for (int ni = 0; ni < 8; ++ni) {
        const float v = acc[mi][ni][j];
        s1 += v; s2 += v * v;
      }
#pragma unroll
      for (int o = 1; o < 16; o <<= 1) {
        s1 += __shfl_xor(s1, o);
        s2 += __shfl_xor(s2, o);
      }
      if (r == 0) {
        const int row = wm * 32 + mi * 16 + kg * 4 + j;
        LSTAT[row][wn] = s1;
        LSTAT[row][4 + wn] = s2;
      }
    }
  __syncthreads();
#pragma unroll
  for (int ni = 0; ni < 8; ++ni) {
    const int col = wn * 128 + ni * 16 + r;
    sc[ni] = s2w[col]; bc[ni] = b2w[col];
  }
#pragma unroll
  for (int mi = 0; mi < 2; ++mi)
#pragma unroll
    for (int j = 0; j < 4; ++j) {
      const int row = wm * 32 + mi * 16 + kg * 4 + j;
      const float S1 = LSTAT[row][0] + LSTAT[row][1] + LSTAT[row][2] + LSTAT[row][3];
      const float S2 = LSTAT[row][4] + LSTAT[row][5] + LSTAT[row][6] + LSTAT[row][7];
      const float mean = S1 * (1.f / 512.f);
      const float var = S2 * (1.f / 512.f) - mean * mean;
      const float rstd = rsqrtf(var + 1e-5f);
#pragma unroll
      for (int ni = 0; ni < 8; ++ni)
        acc[mi][ni][j] = (acc[mi][ni][j] - mean) * rstd * sc[ni] + bc[ni];
    }

#pragma unroll
  for (int mi = 0; mi < 2; ++mi)
#pragma unroll
    for (int ni = 0; ni < 8; ++ni) {
      const int col = wn * 128 + ni * 16 + r;
#pragma unroll
      for (int j = 0; j < 4; ++j) {
        const int row = wm * 32 + mi * 16 + kg * 4 + j;
        EP[row * 516 + col] = f2b(acc[mi][ni][j]);
      }
    }
  __syncthreads();
#pragma unroll
  for (int i = 0; i < 8; ++i) {
    const int t = i * 512 + tid;
    const int row = t >> 6, ch = t & 63;
    *(bf16x8*)&XB[(m0 + row) * 512 + ch * 8] =
        *(const bf16x8*)&EP[row * 516 + ch * 8];
  }
}

// ---------------------------------------------------------------------------
// Fused self-attention: one block per (batch, head).
// ---------------------------------------------------------------------------
__global__ __launch_bounds__(256) void attn_k(const u16* __restrict__ qkv,
                                              const int* __restrict__ tgt,
                                              u16* __restrict__ outp)
{
  __shared__ u16 Qs[64 * 72];
  __shared__ u16 Ks[64 * 72];
  __shared__ u16 Vt[64 * 72];
  __shared__ float S[64 * 65];
  __shared__ int stok[64];

  const int bid = blockIdx.x;
  const int b = bid >> 3, h = bid & 7;
  const int tid = threadIdx.x;
  const int tr = tid >> 2, seg = tid & 3;

  if (tid < 64) stok[tid] = (tid < 61) ? tgt[b * 62 + tid] : -1;

  const long rowbase = ((long)(b * LQ + tr)) * 1536 + h * 64;
  if (tr < LQ) {
    const i4v* qsrc = (const i4v*)(qkv + rowbase + seg * 16);
    i4v q0 = qsrc[0], q1 = qsrc[1];
    *(i4v*)&Qs[tr * 72 + seg * 16] = q0;
    *(i4v*)&Qs[tr * 72 + seg * 16 + 8] = q1;
    const i4v* ksrc = (const i4v*)(qkv + rowbase + 512 + seg * 16);
    i4v k0 = ksrc[0], k1 = ksrc[1];
    *(i4v*)&Ks[tr * 72 + seg * 16] = k0;
    *(i4v*)&Ks[tr * 72 + seg * 16 + 8] = k1;
    const u16* vsrc = qkv + rowbase + 1024 + seg * 16;
#pragma unroll
    for (int i = 0; i < 16; ++i) Vt[(seg * 16 + i) * 72 + tr] = vsrc[i];
  } else {
    i4v zz = {0, 0, 0, 0};
    *(i4v*)&Qs[tr * 72 + seg * 16] = zz;
    *(i4v*)&Qs[tr * 72 + seg * 16 + 8] = zz;
    *(i4v*)&Ks[tr * 72 + seg * 16] = zz;
    *(i4v*)&Ks[tr * 72 + seg * 16 + 8] = zz;
#pragma unroll
    for (int i = 0; i < 16; ++i) Vt[(seg * 16 + i) * 72 + tr] = 0;
  }
  __syncthreads();

  const int lane = tid & 63, w = tid >> 6;
  const int r = lane & 15, kg = lane >> 4;

  {   // QK^T
    f32x4 s[4];
#pragma unroll
    for (int ni = 0; ni < 4; ++ni) s[ni] = (f32x4){0.f, 0.f, 0.f, 0.f};
    bf16x8 a0 = *(const bf16x8*)&Qs[(w * 16 + r) * 72 + kg * 8];
    bf16x8 a1 = *(const bf16x8*)&Qs[(w * 16 + r) * 72 + 32 + kg * 8];
#pragma unroll
    for (int ni = 0; ni < 4; ++ni) {
      bf16x8 b0 = *(const bf16x8*)&Ks[(ni * 16 + r) * 72 + kg * 8];
      bf16x8 b1 = *(const bf16x8*)&Ks[(ni * 16 + r) * 72 + 32 + kg * 8];
      s[ni] = __builtin_amdgcn_mfma_f32_16x16x32_bf16(a0, b0, s[ni], 0, 0, 0);
      s[ni] = __builtin_amdgcn_mfma_f32_16x16x32_bf16(a1, b1, s[ni], 0, 0, 0);
    }
#pragma unroll
    for (int ni = 0; ni < 4; ++ni)
#pragma unroll
      for (int j = 0; j < 4; ++j)
        S[(w * 16 + kg * 4 + j) * 65 + ni * 16 + r] = s[ni][j];
  }
  __syncthreads();

  {   // masked softmax
    const int row = tid >> 2, g = tid & 3;
    float vals[16];
    float mx = -3e38f;
#pragma unroll
    for (int i = 0; i < 16; ++i) {
      const int k = g * 16 + i;
      float v = S[row * 65 + k] * 0.125f;
      const bool ok = (k <= row) && (k < LQ) && (stok[k] != PAD_TOK);
      v = ok ? v : -1e30f;
      vals[i] = v;
      mx = fmaxf(mx, v);
    }
    mx = fmaxf(mx, __shfl_xor(mx, 1));
    mx = fmaxf(mx, __shfl_xor(mx, 2));
    float sum = 0.f;
#pragma unroll
    for (int i = 0; i < 16; ++i) { float e = __expf(vals[i] - mx); vals[i] = e; sum += e; }
    sum += __shfl_xor(sum, 1);
    sum += __shfl_xor(sum, 2);
    const float inv = 1.f / sum;
#pragma unroll
    for (int i = 0; i < 16; ++i) Qs[row * 72 + g * 16 + i] = f2b(vals[i] * inv);
  }
  __syncthreads();

  {   // PV, swizzled bounce into Ks
    f32x4 o[4];
#pragma unroll
    for (int ni = 0; ni < 4; ++ni) o[ni] = (f32x4){0.f, 0.f, 0.f, 0.f};
    bf16x8 a0 = *(const bf16x8*)&Qs[(w * 16 + r) * 72 + kg * 8];
    bf16x8 a1 = *(const bf16x8*)&Qs[(w * 16 + r) * 72 + 32 + kg * 8];
#pragma unroll
    for (int ni = 0; ni < 4; ++ni) {
      bf16x8 b0 = *(const bf16x8*)&Vt[(ni * 16 + r) * 72 + kg * 8];
      bf16x8 b1 = *(const bf16x8*)&Vt[(ni * 16 + r) * 72 + 32 + kg * 8];
      o[ni] = __builtin_amdgcn_mfma_f32_16x16x32_bf16(a0, b0, o[ni], 0, 0, 0);
      o[ni] = __builtin_amdgcn_mfma_f32_16x16x32_bf16(a1, b1, o[ni], 0, 0, 0);
    }
#pragma unroll
    for (int ni = 0; ni < 4; ++ni)
#pragma unroll
      for (int j = 0; j < 4; ++j) {
        const int qrow = w * 16 + kg * 4 + j;
        const int col = ni * 16 + r;
        Ks[qrow * 64 + (col ^ ((qrow & 7) << 3))] = f2b(o[ni][j]);
      }
  }
  __syncthreads();

  {   // coalesced O store
    const int row = tid >> 2, sub = tid & 3;
    if (row < LQ) {
      const long obase = ((long)(b * LQ + row)) * 512 + h * 64;
#pragma unroll
      for (int i = 0; i < 2; ++i) {
        const int ch = i * 4 + sub;
        const int phys = ch ^ (row & 7);
        bf16x8 vv = *(const bf16x8*)&Ks[row * 64 + phys * 8];
        *(bf16x8*)&outp[obase + ch * 8] = vv;
      }
    }
  }
}

__device__ __forceinline__ void ln_row(f4& v0, f4& v1,
                                       const float* __restrict__ sw,
                                       const float* __restrict__ bw, int d0) {
  float s1 = v0[0] + v0[1] + v0[2] + v0[3] + v1[0] + v1[1] + v1[2] + v1[3];
  float s2 = v0[0]*v0[0] + v0[1]*v0[1] + v0[2]*v0[2] + v0[3]*v0[3]
           + v1[0]*v1[0] + v1[1]*v1[1] + v1[2]*v1[2] + v1[3]*v1[3];
#pragma unroll
  for (int off = 1; off < 64; off <<= 1) {
    s1 += __shfl_xor(s1, off);
    s2 += __shfl_xor(s2, off);
  }
  const float mean = s1 * (1.f / 512.f);
  const float var = s2 * (1.f / 512.f) - mean * mean;
  const float rstd = rsqrtf(var + 1e-5f);
  const f4* sp = (const f4*)(sw + d0);
  const f4* bp = (const f4*)(bw + d0);
  f4 ss0 = sp[0], ss1 = sp[1], bb0 = bp[0], bb1 = bp[1];
#pragma unroll
  for (int i = 0; i < 4; ++i) {
    v0[i] = (v0[i] - mean) * rstd * ss0[i] + bb0[i];
    v1[i] = (v1[i] - mean) * rstd * ss1[i] + bb1[i];
  }
}

// lnf3: XB = LN(p + XB)
__global__ __launch_bounds__(256) void lnf3_k(const u16* __restrict__ p,
                                              const u16* __restrict__ xr,
                                              const float* __restrict__ s1,
                                              const float* __restrict__ b1,
                                              u16* __restrict__ out)
{
  const int m = blockIdx.x * 4 + (threadIdx.x >> 6);
  const int lane = threadIdx.x & 63;
  const int d0 = lane * 8;
  bf16x8 pv = *(const bf16x8*)(p + (long)m * 512 + d0);
  bf16x8 xv = *(const bf16x8*)(xr + (long)m * 512 + d0);
  f4 v0, v1;
#pragma unroll
  for (int i = 0; i < 4; ++i) {
    v0[i] = b2f((u16)pv[i]) + b2f((u16)xv[i]);
    v1[i] = b2f((u16)pv[4 + i]) + b2f((u16)xv[4 + i]);
  }
  ln_row(v0, v1, s1, b1, d0);
  u16x4* ob = (u16x4*)(out + (long)m * 512 + d0);
  ob[0] = cvt4(v0);
  ob[1] = cvt4(v1);
}

// Embedding: xb[m] = bf16(emb[tok] + point_out[b] + pos_embed[t])
__global__ __launch_bounds__(256) void embed_k(const float* __restrict__ emb,
                                               const float* __restrict__ pout,
                                               const float* __restrict__ pos,
                                               const int* __restrict__ tgt,
                                               u16* __restrict__ XB)
{
  const int m = blockIdx.x * 4 + (threadIdx.x >> 6);
  const int lane = threadIdx.x & 63;
  const int b = m / LQ, t = m % LQ;
  const int tok = tgt[b * 62 + t];
  const int d0 = lane * 8;
  const f4* e = (const f4*)(emb + (long)tok * 512 + d0);
  const f4* p = (const f4*)(pout + (long)b * 512 + d0);
  const f4* q = (const f4*)(pos + (long)t * 512 + d0);
  f4 v0 = e[0] + p[0] + q[0];
  f4 v1 = e[1] + p[1] + q[1];
  u16x4* xb = (u16x4*)(XB + (long)m * 512 + d0);
  xb[0] = cvt4(v0);
  xb[1] = cvt4(v1);
}

// single merged preamble conversion kernel (all weights + mem + out pads)
__global__ void cvtall_k(const float* __restrict__ sa_inw, const float* __restrict__ sa_outw,
                         const float* __restrict__ ca_outw, const float* __restrict__ ff1_w,
                         const float* __restrict__ ff2_w, const float* __restrict__ ca_inw,
                         const float* __restrict__ out_w, const float* __restrict__ out_b,
                         const float* __restrict__ enc,
                         u16* __restrict__ WSA, u16* __restrict__ WSO,
                         u16* __restrict__ WCO, u16* __restrict__ WF1,
                         u16* __restrict__ WF2, u16* __restrict__ WCAV,
                         u16* __restrict__ WOUT, float* __restrict__ BOUT,
                         u16* __restrict__ MEMB)
{
  const int C0 = 320;                 // out_b -> BOUT[1280] f32
  const int C1 = C0 + 32768;          // enc row0 -> MEMB
  const int C2 = C1 + 163840;         // out_w -> WOUT [1280][512] padded
  const int C3 = C2 + 393216;         // ca_inw v-slice -> WCAV
  const int C4 = C3 + 1179648;        // sa_inw
  const int C5 = C4 + 393216;         // sa_outw
  const int C6 = C5 + 393216;         // ca_outw
  const int C7 = C6 + 1572864;        // ff1_w
  const int C8 = C7 + 1572864;        // ff2_w
  for (int i = blockIdx.x * 256 + threadIdx.x; i < C8; i += gridDim.x * 256) {
    if (i < C0) {
      const int base = i * 4;
#pragma unroll
      for (int e = 0; e < 4; ++e)
        BOUT[base + e] = (base + e < 1027) ? out_b[base + e] : 0.f;
    } else if (i < C1) {
      const int k = i - C0;
      const int b = (k * 4) >> 9, d = (k * 4) & 511;
      f4 v = ((const f4*)enc)[(b * 8192 + d) >> 2];
      ((u16x4*)MEMB)[k] = cvt4(v);
    } else if (i < C2) {
      const int k = i - C1;
      const int row = (k * 4) >> 9;
      u16x4 o = {0, 0, 0, 0};
      if (row < 1027) { f4 v = ((const f4*)out_w)[k]; o = cvt4(v); }
      ((u16x4*)WOUT)[k] = o;
    } else if (i < C3) {
      const int k = i - C2;
      const int l = k >> 16, rem = k & 65535;
      f4 v = ((const f4*)ca_inw)[l * 196608 + 131072 + rem];
      ((u16x4*)WCAV)[k] = cvt4(v);
    } else {
      const float* s; u16* d; int k;
      if (i < C4)      { s = sa_inw;  d = WSA; k = i - C3; }
      else if (i < C5) { s = sa_outw; d = WSO; k = i - C4; }
      else if (i < C6) { s = ca_outw; d = WCO; k = i - C5; }
      else if (i < C7) { s = ff1_w;   d = WF1; k = i - C6; }
      else             { s = ff2_w;   d = WF2; k = i - C7; }
      f4 v = ((const f4*)s)[k];
      ((u16x4*)d)[k] = cvt4(v);
    }
  }
}

// ---------------------------------------------------------------------------
// Workspace layout (bytes)
// ---------------------------------------------------------------------------
static constexpr size_t XB_OFF    = 0;            // bf16 [15616][512]
static constexpr size_t P_OFF     = 15990784;     // bf16 [15616][512]
static constexpr size_t BIG_OFF   = 31981568;     // bf16 qkv/h1
static constexpr size_t ATT_OFF   = 95944704;     // bf16 [15616][512]
static constexpr size_t WSA_OFF   = 111935488;    // bf16 [6][1536][512]
static constexpr size_t WSO_OFF   = 121372672;    // bf16 [6][512][512]
static constexpr size_t WCAV_OFF  = 124518400;    // bf16 [6][512][512]
static constexpr size_t WCO_OFF   = 127664128;    // bf16 [6][512][512]
static constexpr size_t WF1_OFF   = 130809856;    // bf16 [6][2048][512]
static constexpr size_t WF2_OFF   = 143392768;    // bf16 [6][512][2048]
static constexpr size_t WOUT_OFF  = 155975680;    // bf16 [1280][512]
static constexpr size_t BOUT_OFF  = 157286400;    // f32  [1280]
static constexpr size_t MEMB_OFF  = 157291520;    // bf16 [256][512]
static constexpr size_t CATMP_OFF = 157553664;    // bf16 [6][256][512]
static constexpr size_t CAVB_OFF  = 159126528;    // bf16 [6][256][512]

extern "C" void kernel_launch(void* const* d_in, const int* in_sizes, int n_in,
                              void* d_out, int out_size, void* d_ws, size_t ws_size,
                              hipStream_t stream) {
  (void)in_sizes; (void)n_in; (void)out_size; (void)ws_size;
  const float* encoder_out = (const float*)d_in[0];
  const float* point_out   = (const float*)d_in[1];
  const float* emb         = (const float*)d_in[2];
  const float* pos         = (const float*)d_in[3];
  const float* sa_inw      = (const float*)d_in[4];
  const float* sa_inb      = (const float*)d_in[5];
  const float* sa_outw     = (const float*)d_in[6];
  const float* sa_outb     = (const float*)d_in[7];
  const float* ca_inw      = (const float*)d_in[8];
  const float* ca_inb      = (const float*)d_in[9];
  const float* ca_outw     = (const float*)d_in[10];
  const float* ca_outb     = (const float*)d_in[11];
  const float* ln1_s       = (const float*)d_in[12];
  const float* ln1_b       = (const float*)d_in[13];
  const float* ln2_s       = (const float*)d_in[14];
  const float* ln2_b       = (const float*)d_in[15];
  const float* ln3_s       = (const float*)d_in[16];
  const float* ln3_b       = (const float*)d_in[17];
  const float* ff1_w       = (const float*)d_in[18];
  const float* ff1_b       = (const float*)d_in[19];
  const float* ff2_w       = (const float*)d_in[20];
  const float* ff2_b       = (const float*)d_in[21];
  const float* out_w       = (const float*)d_in[22];
  const float* out_b       = (const float*)d_in[23];
  const int*   tgt         = (const int*)d_in[24];

  char* ws = (char*)d_ws;
  u16*   XB    = (u16*)(ws + XB_OFF);
  u16*   P     = (u16*)(ws + P_OFF);
  u16*   BIG   = (u16*)(ws + BIG_OFF);
  u16*   ATT   = (u16*)(ws + ATT_OFF);
  u16*   WSA   = (u16*)(ws + WSA_OFF);
  u16*   WSO   = (u16*)(ws + WSO_OFF);
  u16*   WCAV  = (u16*)(ws + WCAV_OFF);
  u16*   WCO   = (u16*)(ws + WCO_OFF);
  u16*   WF1   = (u16*)(ws + WF1_OFF);
  u16*   WF2   = (u16*)(ws + WF2_OFF);
  u16*   WOUT  = (u16*)(ws + WOUT_OFF);
  float* BOUT  = (float*)(ws + BOUT_OFF);
  u16*   MEMB  = (u16*)(ws + MEMB_OFF);
  u16*   CATMP = (u16*)(ws + CATMP_OFF);
  u16*   CAVB  = (u16*)(ws + CAVB_OFF);

  // ---- merged weight/preamble conversion ----
  cvtall_k<<<dim3(2048), dim3(256), 0, stream>>>(
      sa_inw, sa_outw, ca_outw, ff1_w, ff2_w, ca_inw, out_w, out_b, encoder_out,
      WSA, WSO, WCO, WF1, WF2, WCAV, WOUT, BOUT, MEMB);

  // ---- embedding ----
  embed_k<<<dim3(MTOT / 4), dim3(256), 0, stream>>>(emb, point_out, pos, tgt, XB);

  // ---- cross-attention vectors (x-independent), bf16 ----
  gemm_bt<64><<<dim3(4, 4, 6), dim3(256), 0, stream>>>(
      MEMB, WCAV, ca_inb + 1024, nullptr, CATMP,
      256, 512, 512, 512, 512, 0,
      0L, 262144L, 1536L, 131072L);
  gemm_bt<64><<<dim3(4, 4, 6), dim3(256), 0, stream>>>(
      CATMP, WCO, ca_outb, nullptr, CAVB,
      256, 512, 512, 512, 512, 0,
      131072L, 262144L, 512L, 131072L);

  for (int l = 0; l < 6; ++l) {
    // QKV: 128x256 tiles, grid 6x122
    gemm_bt2<<<dim3(6, 122), dim3(512), 0, stream>>>(
        XB, WSA + (long)l * 786432, sa_inb + l * 1536, nullptr, BIG,
        1536, 512, 1536, 1536, 0);
    // fused attention
    attn_k<<<dim3(2048), dim3(256), 0, stream>>>(BIG, tgt, ATT);
    // out-proj + resid + LN1 + CA + LN2 -> XB (fused full-row, K=512)
    gemmln_k<<<dim3(244), dim3(512), 0, stream>>>(
        ATT, WSO + (long)l * 262144, sa_outb + l * 512,
        CAVB + (long)l * 131072,
        ln1_s + l * 512, ln1_b + l * 512, ln2_s + l * 512, ln2_b + l * 512,
        XB, 512);
    // FF1 + ReLU: 128x256 tiles, grid 8x122
    gemm_bt2<<<dim3(8, 122), dim3(512), 0, stream>>>(
        XB, WF1 + (long)l * 1048576, ff1_b + l * 2048, nullptr, BIG,
        2048, 512, 2048, 2048, 1);
    // FF2 -> P : 64x256 tiles, grid 2x244 (halved N-split vs BN=128)
    gemm_bt3<<<dim3(2, 244), dim3(512), 0, stream>>>(
        BIG, WF2 + (long)l * 1048576, ff2_b + l * 512, P,
        512, 2048, 0);
    // resid + LN3 -> XB
    lnf3_k<<<dim3(MTOT / 4), dim3(256), 0, stream>>>(
        P, XB, ln3_s + l * 512, ln3_b + l * 512, XB);
  }

  // ---- final logits: 128x256 tiles, N padded 1280, f32 bounce epilogue ----
  gemm_bt2<<<dim3(5, 122), dim3(512), 0, stream>>>(
      XB, WOUT, BOUT, (float*)d_out, nullptr,
      1280, 512, 1027, 1027, 0);
}